// Round 22
// baseline (6593.925 us; speedup 1.0000x reference)
//
#include <hip/hip_runtime.h>

// SimplePerformer forward: fused-LN bf16-MFMA GEMMs + 3-kernel exact FAVOR+.
// Round 22: gemm_ln counted-vmcnt pipeline (T4): raw s_barrier + vmcnt(5),
// prefetched chunk stays in flight across barriers (r18's __syncthreads
// drained it).  LDS exactly 80KB (red aliases As).  Rest identical to r21.
// B=8 G=20000 D=256 H=8 DH=32 L=4 M=128 FF=1024
#define Bb 8
#define Gg 20000
#define Dd 256
#define Hh 8
#define DHh 32
#define Ll 4
#define Mm 128
#define FFf 1024
#define QKVS 768   // fused qkv row stride: [k | v | q]
#define NBLK 192   // rows per attention block
#define NSLOT 105  // ceil(20000/192) blocks per head

typedef __attribute__((ext_vector_type(8))) short bf16x8;
typedef __attribute__((ext_vector_type(4))) float f32x4;

#define DN    0.4204482076268573f     /* 32^-0.25 */
#define DN2H  0.088388347648318447f   /* 0.5 * 32^-0.5 */
#define RATIO 0.08838834764831845f    /* 128^-0.5 */
#define EPSK  1e-4f

__device__ __forceinline__ float geluf(float x) {
    return 0.5f * x * (1.0f + erff(x * 0.70710678118654752f));
}
__device__ __forceinline__ float bf2f(ushort u) {
    union { uint i; float f; } v; v.i = ((uint)u) << 16; return v.f;
}
__device__ __forceinline__ ushort f2bf(float f) {
    union { float f; uint i; } v; v.f = f;
    uint i = v.i;
    return (ushort)((i + 0x7FFFu + ((i >> 16) & 1u)) >> 16);   // RNE
}
__device__ __forceinline__ void gload16(const void* g, void* l) {
    __builtin_amdgcn_global_load_lds(
        (const __attribute__((address_space(1))) void*)g,
        (__attribute__((address_space(3))) void*)l, 16, 0, 0);
}

// ------------------------------------------------- batched weight casts
__global__ __launch_bounds__(256) void k_wt4(const float* __restrict__ wk,
    const float* __restrict__ wv, const float* __restrict__ wq,
    const float* __restrict__ wo, ushort* __restrict__ Wt)
{
    const int z = blockIdx.z, l = z >> 2, wh = z & 3;
    const float* src = (wh == 0) ? wk : (wh == 1) ? wv : (wh == 2) ? wq : wo;
    src += (size_t)l * 65536;
    ushort* d = Wt + (size_t)l * 786432 + (size_t)wh * 65536;
    __shared__ float tl[32][33];
    const int n0 = blockIdx.x * 32, k0 = blockIdx.y * 32;
    const int tx = threadIdx.x & 31, ty = threadIdx.x >> 5;
#pragma unroll
    for (int i = 0; i < 4; i++)
        tl[ty + i*8][tx] = src[(size_t)(k0 + ty + i*8) * 256 + n0 + tx];
    __syncthreads();
#pragma unroll
    for (int i = 0; i < 4; i++)
        d[(size_t)(n0 + ty + i*8) * 256 + k0 + tx] = f2bf(tl[tx][ty + i*8]);
}

__global__ __launch_bounds__(256) void k_wtA(const float* __restrict__ ff1,
    const float* __restrict__ pw1, const float* __restrict__ hw1,
    ushort* __restrict__ Wt)
{
    const int z = blockIdx.z;
    const float* src; ushort* d;
    if (z < 4)      { src = ff1 + (size_t)z*262144; d = Wt + (size_t)z*786432 + 262144; }
    else if (z == 4){ src = pw1; d = Wt + (size_t)4*786432; }
    else            { src = hw1; d = Wt + (size_t)4*786432 + 524288; }
    __shared__ float tl[32][33];
    const int n0 = blockIdx.x * 32, k0 = blockIdx.y * 32;
    const int tx = threadIdx.x & 31, ty = threadIdx.x >> 5;
#pragma unroll
    for (int i = 0; i < 4; i++)
        tl[ty + i*8][tx] = src[(size_t)(k0 + ty + i*8) * 1024 + n0 + tx];
    __syncthreads();
#pragma unroll
    for (int i = 0; i < 4; i++)
        d[(size_t)(n0 + ty + i*8) * 256 + k0 + tx] = f2bf(tl[tx][ty + i*8]);
}

__global__ __launch_bounds__(256) void k_wtB(const float* __restrict__ ff2,
    const float* __restrict__ pw2, ushort* __restrict__ Wt)
{
    const int z = blockIdx.z;
    const float* src; ushort* d;
    if (z < 4) { src = ff2 + (size_t)z*262144; d = Wt + (size_t)z*786432 + 524288; }
    else       { src = pw2; d = Wt + (size_t)4*786432 + 262144; }
    __shared__ float tl[32][33];
    const int n0 = blockIdx.x * 32, k0 = blockIdx.y * 32;
    const int tx = threadIdx.x & 31, ty = threadIdx.x >> 5;
#pragma unroll
    for (int i = 0; i < 4; i++)
        tl[ty + i*8][tx] = src[(size_t)(k0 + ty + i*8) * 256 + n0 + tx];
    __syncthreads();
#pragma unroll
    for (int i = 0; i < 4; i++)
        d[(size_t)(n0 + ty + i*8) * 1024 + k0 + tx] = f2bf(tl[tx][ty + i*8]);
}

__global__ __launch_bounds__(256) void k_pcast(const float* __restrict__ src,
    ushort* __restrict__ dst, int n)
{
    int i = blockIdx.x*256 + threadIdx.x;
    if (i < n) dst[i] = f2bf(src[i]);
}

// pnorm[l] = max_m ||proj[l,m,:]||_2   grid (4), 128 thr
__global__ __launch_bounds__(128) void k_pn(const float* __restrict__ featp,
    float* __restrict__ pnorm)
{
    const int l = blockIdx.x, t = threadIdx.x;
    const float* p = featp + (size_t)l*4096 + t*32;
    float s = 0.f;
#pragma unroll
    for (int d = 0; d < 32; d++) s += p[d]*p[d];
#pragma unroll
    for (int off = 1; off < 64; off <<= 1) s = fmaxf(s, __shfl_xor(s, off));
    __shared__ float sm2[2];
    if ((t & 63) == 0) sm2[t >> 6] = s;
    __syncthreads();
    if (t == 0) pnorm[l] = sqrtf(fmaxf(sm2[0], sm2[1]));
}

// ------------------------------------------------- bf16 MFMA GEMM 128x128
// 512 thr (8 waves 2Mx4N, wave tile 64x32), BK=64, single-buffer 32KB LDS.
__global__ __launch_bounds__(512) void gemm_bf(
    const ushort* __restrict__ A, const ushort* __restrict__ Bt,
    const float* __restrict__ bias, ushort* __restrict__ C,
    int Mrows, int N, int K, int act)
{
    __shared__ ushort As[8192];   // [8 rg][2 kg][512]
    __shared__ ushort Bs[8192];
    const int t = threadIdx.x;
    const int l = t & 63, wid = t >> 6;        // 8 waves
    const int lr = l & 15, q = l >> 4;
    const int wm = wid >> 2, wn = wid & 3;     // 2 x 4 wave grid
    const int row0 = blockIdx.y * 128, col0 = blockIdx.x * 128;

    const int sar = min(row0 + wid*16 + lr, Mrows - 1);
    const ushort* gA = A  + (size_t)sar * K + q*8;
    const ushort* gB = Bt + (size_t)(col0 + wid*16 + lr) * K + q*8;
    ushort* lA = As + wid*1024;
    ushort* lB = Bs + wid*1024;

    f32x4 acc[4][2] = {};

    for (int k0 = 0; k0 < K; k0 += 64) {
        __syncthreads();               // prev-chunk reads done
        gload16(gA + k0,      lA);
        gload16(gA + k0 + 32, lA + 512);
        gload16(gB + k0,      lB);
        gload16(gB + k0 + 32, lB + 512);
        __syncthreads();               // stage complete
#pragma unroll
        for (int kg = 0; kg < 2; kg++) {
            bf16x8 af[4];
#pragma unroll
            for (int mi = 0; mi < 4; mi++)
                af[mi] = *(const bf16x8*)&As[((wm*4 + mi)*2 + kg)*512 + l*8];
#pragma unroll
            for (int ni = 0; ni < 2; ni++) {
                bf16x8 bv = *(const bf16x8*)&Bs[((wn*2 + ni)*2 + kg)*512 + l*8];
#pragma unroll
                for (int mi = 0; mi < 4; mi++)
                    acc[mi][ni] = __builtin_amdgcn_mfma_f32_16x16x32_bf16(
                        af[mi], bv, acc[mi][ni], 0, 0, 0);
            }
        }
    }

#pragma unroll
    for (int mi = 0; mi < 4; mi++)
#pragma unroll
        for (int j = 0; j < 4; j++) {
            int row = row0 + wm*64 + mi*16 + q*4 + j;
            if (row >= Mrows) continue;
#pragma unroll
            for (int ni = 0; ni < 2; ni++) {
                int col = col0 + wn*32 + ni*16 + lr;
                float v = acc[mi][ni][j];
                if (bias) v += bias[col];
                if (act == 1) v = fmaxf(v, 0.f);
                else if (act == 2) v = geluf(v);
                C[(size_t)row * N + col] = f2bf(v);
            }
        }
}

// ------------------------------------------------- GEMM + LayerNorm fusion
// v = A@Bt + bias [+res] [+Cout_old];  Cout=v (fp32);  ABout=LN(v) (bf16).
// 512 thr (8 waves 2Mx4N, wave tile 32x64), BM=64 BN=256 BK=64.
// Counted-vmcnt 2-buffer pipeline: each wave issues exactly 5 gload16/chunk;
// vmcnt(5) at loop top keeps the next chunk in flight across the barrier.
__global__ __launch_bounds__(512) void gemm_ln(
    const ushort* __restrict__ A, const ushort* __restrict__ Bt,
    const float* __restrict__ bias, const float* __restrict__ res,
    float* __restrict__ Cout, ushort* __restrict__ ABout,
    const float* __restrict__ gam, const float* __restrict__ bet,
    int Mrows, int K, int addC)
{
    __shared__ ushort As[2][4096];    // 2 x (64 rows x 64 k)  = 16KB
    __shared__ ushort Bs[2][16384];   // 2 x (256 cols x 64 k) = 64KB
    const int t = threadIdx.x, l = t & 63, wid = t >> 6;
    const int lr = l & 15, lq = l >> 4;
    const int wm = wid >> 2, wn = wid & 3;     // 2 x 4 wave grid
    const int row0 = blockIdx.x * 64;

    // staging: wave wid fills A-group wid (rg=wid>>1, kg=wid&1) + B-groups wid*4..+3
    const int sar = min(row0 + (wid >> 1)*16 + lr, Mrows - 1);
    const ushort* gA = A + (size_t)sar * K + (wid & 1)*32 + lq*8;
    const ushort* gB[4];
#pragma unroll
    for (int i = 0; i < 4; i++) {
        int g = wid*4 + i;
        gB[i] = Bt + (size_t)((g >> 1)*16 + lr) * K + (g & 1)*32 + lq*8;
    }

    f32x4 acc[2][4] = {};
    const int nk = K >> 6;

    // prologue: stage chunks 0 and 1 (5 loads each per wave -> 10 in flight)
    gload16(gA, As[0] + wid*512);
#pragma unroll
    for (int i = 0; i < 4; i++) gload16(gB[i], Bs[0] + (wid*4 + i)*512);
    if (nk > 1) {
        gload16(gA + 64, As[1] + wid*512);
#pragma unroll
        for (int i = 0; i < 4; i++) gload16(gB[i] + 64, Bs[1] + (wid*4 + i)*512);
    }

    for (int c = 0; c < nk; c++) {
        // wait only for chunk c's 5 loads; chunk c+1's 5 stay in flight
        if (c < nk - 1) asm volatile("s_waitcnt vmcnt(5)" ::: "memory");
        else            asm volatile("s_waitcnt vmcnt(0)" ::: "memory");
        __builtin_amdgcn_sched_barrier(0);
        __builtin_amdgcn_s_barrier();      // all waves' chunk-c data in LDS
        __builtin_amdgcn_sched_barrier(0);
        const ushort* Ap = As[c & 1];
        const ushort* Bp = Bs[c & 1];
#pragma unroll
        for (int kg = 0; kg < 2; kg++) {
            bf16x8 af[2];
#pragma unroll
            for (int mi = 0; mi < 2; mi++)
                af[mi] = *(const bf16x8*)&Ap[((wm*2 + mi)*2 + kg)*512 + l*8];
#pragma unroll
            for (int ni = 0; ni < 4; ni++) {
                bf16x8 bv = *(const bf16x8*)&Bp[((wn*4 + ni)*2 + kg)*512 + l*8];
#pragma unroll
                for (int mi = 0; mi < 2; mi++)
                    acc[mi][ni] = __builtin_amdgcn_mfma_f32_16x16x32_bf16(
                        af[mi], bv, acc[mi][ni], 0, 0, 0);
            }
        }
        __builtin_amdgcn_sched_barrier(0);
        __builtin_amdgcn_s_barrier();      // all waves done reading buf[c&1]
        __builtin_amdgcn_sched_barrier(0);
        if (c + 2 < nk) {                  // re-stage freed buffer; flies ~1 iter
            int ko = (c + 2) * 64;
            gload16(gA + ko, As[c & 1] + wid*512);
#pragma unroll
            for (int i = 0; i < 4; i++)
                gload16(gB[i] + ko, Bs[c & 1] + (wid*4 + i)*512);
        }
    }

    __syncthreads();   // drain; reuse As[0] as reduction scratch
    float* red1 = (float*)(&As[0][0]);     // [4][64]
    float* red2 = red1 + 256;              // [4][64]

    // epilogue: bias/res/addC -> LN stats (cross-wave over wn) -> dual write
    float biasv[4], gv[4], bvv[4];
#pragma unroll
    for (int ni = 0; ni < 4; ni++) {
        int col = wn*64 + ni*16 + lr;
        biasv[ni] = bias[col]; gv[ni] = gam[col]; bvv[ni] = bet[col];
    }
#pragma unroll
    for (int mi = 0; mi < 2; mi++)
#pragma unroll
        for (int j = 0; j < 4; j++) {
            int row = row0 + wm*32 + mi*16 + lq*4 + j;
            bool ok = row < Mrows;
#pragma unroll
            for (int ni = 0; ni < 4; ni++) {
                float v = acc[mi][ni][j] + biasv[ni];
                size_t ci = (size_t)row * 256 + wn*64 + ni*16 + lr;
                if (ok) {
                    if (res)  v += res[ci];
                    if (addC) v += Cout[ci];
                }
                acc[mi][ni][j] = v;
            }
        }
#pragma unroll
    for (int mi = 0; mi < 2; mi++)
#pragma unroll
        for (int j = 0; j < 4; j++) {
            float s1 = 0.f, s2 = 0.f;
#pragma unroll
            for (int ni = 0; ni < 4; ni++) {
                float v = acc[mi][ni][j];
                s1 += v; s2 += v*v;
            }
#pragma unroll
            for (int off = 1; off < 16; off <<= 1) {
                s1 += __shfl_xor(s1, off);
                s2 += __shfl_xor(s2, off);
            }
            if (lr == 0) {
                int r = wm*32 + mi*16 + lq*4 + j;
                red1[wn*64 + r] = s1;
                red2[wn*64 + r] = s2;
            }
        }
    __syncthreads();
#pragma unroll
    for (int mi = 0; mi < 2; mi++)
#pragma unroll
        for (int j = 0; j < 4; j++) {
            int r = wm*32 + mi*16 + lq*4 + j;
            int row = row0 + r;
            if (row >= Mrows) continue;
            float m1 = (red1[r]+red1[64+r]+red1[128+r]+red1[192+r]) * (1.f/256.f);
            float m2 = (red2[r]+red2[64+r]+red2[128+r]+red2[192+r]) * (1.f/256.f);
            float inv = rsqrtf(m2 - m1*m1 + 1e-5f);
#pragma unroll
            for (int ni = 0; ni < 4; ni++) {
                size_t ci = (size_t)row * 256 + wn*64 + ni*16 + lr;
                float v = acc[mi][ni][j];
                Cout[ci] = v;
                ABout[ci] = f2bf((v - m1)*inv*gv[ni] + bvv[ni]);
            }
        }
}

// ------------------------------------------------- sample embedding (split)
__global__ __launch_bounds__(256) void k_zero(float* __restrict__ p, int n) {
    int i = blockIdx.x*256 + threadIdx.x;
    if (i < n) p[i] = 0.f;
}

__global__ __launch_bounds__(256) void k_se1(const float* __restrict__ x,
    const float* __restrict__ w1, float* __restrict__ t1)
{
    const int blk = blockIdx.x, b = blockIdx.y, t = threadIdx.x;
    const int k0 = blk * 250;
    float acc = 0.f;
    for (int kk = 0; kk < 250; kk++) {
        float xv = x[b*Gg + k0 + kk];
        acc += xv * w1[(size_t)(k0 + kk)*256 + t];
    }
    atomicAdd(&t1[b*256 + t], acc);
}

__global__ __launch_bounds__(256) void k_se2(const float* __restrict__ t1,
    const float* __restrict__ b1, const float* __restrict__ w2,
    const float* __restrict__ b2, float* __restrict__ samp)
{
    const int b = blockIdx.x, t = threadIdx.x;
    __shared__ float s1[256];
    s1[t] = fmaxf(t1[b*256 + t] + b1[t], 0.f);
    __syncthreads();
    float acc = 0.f;
    for (int n = 0; n < 256; n++) acc += s1[n] * w2[(size_t)n*256 + t];
    samp[b*256 + t] = acc + b2[t];
}

// embed: one wave per row, 4 cols/lane.  grid (MB/4); batch decoded from row.
__global__ __launch_bounds__(256) void k_embed(const float* __restrict__ x,
    const float* __restrict__ gene_emb, const float* __restrict__ samp,
    ushort* __restrict__ outb, int b0)
{
    const int w = threadIdx.x >> 6, l = threadIdx.x & 63;
    const int mb = blockIdx.x * 4 + w;          // row within this pass
    const int bb = mb / Gg;                     // 0..NBP-1
    const int g  = mb - bb * Gg;
    const int b  = b0 + bb;
    const float xv = x[b*Gg + g];
    const int d0 = l * 4;
    float4 gev = *(const float4*)&gene_emb[(size_t)g*256 + d0];
    float4 sv  = *(const float4*)&samp[b*256 + d0];
    float gv[4] = {gev.x, gev.y, gev.z, gev.w};
    float sp[4] = {sv.x, sv.y, sv.z, sv.w};
    ushort4 o;
    ushort* op = (ushort*)&o;
#pragma unroll
    for (int i = 0; i < 4; i++) {
        int d = d0 + i, j = d & 127;
        float ang = xv * __expf(-(float)j * 0.035977892078032f);   // ln(100)/128
        float ree = (d < 128) ? __sinf(ang) : __cosf(ang);
        if (xv == -10.0f) ree = 0.f;
        op[i] = f2bf(gv[i] + ree + sp[i]);
    }
    *(ushort4*)&outb[(size_t)mb*256 + d0] = o;
}

// ------------------------------------------------- FAVOR+ (3 kernels, exact)
// ctx2: norm-bound local shift + E-sums + Sv + slot stores.  grid (NSLOT, 8*NBP)
__global__ __launch_bounds__(256) void k_ctx2(const ushort* __restrict__ qkv,
    const ushort* __restrict__ projb, const float* __restrict__ pnorm, int lidx,
    float* __restrict__ ctxp, float* __restrict__ ksp, float* __restrict__ svp,
    float* __restrict__ mlp)
{
    __shared__ ushort kpsT[128][72];
    __shared__ ushort vt[32][72];
    __shared__ float diag[192];
    __shared__ float sm[4];
    __shared__ float ksl[4][128];
    __shared__ float svl[8][32];
    const int bh = blockIdx.y, blk = blockIdx.x;
    const int h = bh & 7;
    const ushort* qkvb = qkv + (size_t)(bh >> 3) * Gg * QKVS;
    const int t = threadIdx.x, w = t >> 6, l = t & 63;
    const int lr = l & 15, lq = l >> 4;
    bf16x8 pb[8];
#pragma unroll
    for (int nt = 0; nt < 8; nt++)
        pb[nt] = *(const bf16x8*)(projb + (nt*16 + lr)*32 + lq*8);
    const int g0 = blk * NBLK;
    const int rows = min(NBLK, Gg - g0);
    f32x4 z = {};

    // ---- pass 0: load k-frags, row norms -> diag LDS + block max norm
    bf16x8 afs0 = {}, afs1 = {}, afs2 = {};
    float mx = 0.f;
    {
        int arow = min(g0 + w*16 + lr, Gg - 1);
        afs0 = *(const bf16x8*)(qkvb + (size_t)arow*QKVS + h*32 + lq*8);
        float s = 0.f;
#pragma unroll
        for (int j = 0; j < 8; j++) { float kv = bf2f((ushort)afs0[j]); s += kv*kv; }
        s += __shfl_xor(s, 16); s += __shfl_xor(s, 32);
        if (l < 16) diag[w*16 + l] = DN2H * s;
        mx = fmaxf(mx, s);
    }
    if (64 < rows) {
        int arow = min(g0 + 64 + w*16 + lr, Gg - 1);
        afs1 = *(const bf16x8*)(qkvb + (size_t)arow*QKVS + h*32 + lq*8);
        float s = 0.f;
#pragma unroll
        for (int j = 0; j < 8; j++) { float kv = bf2f((ushort)afs1[j]); s += kv*kv; }
        s += __shfl_xor(s, 16); s += __shfl_xor(s, 32);
        if (l < 16) diag[64 + w*16 + l] = DN2H * s;
        mx = fmaxf(mx, s);
    }
    if (128 < rows) {
        int arow = min(g0 + 128 + w*16 + lr, Gg - 1);
        afs2 = *(const bf16x8*)(qkvb + (size_t)arow*QKVS + h*32 + lq*8);
        float s = 0.f;
#pragma unroll
        for (int j = 0; j < 8; j++) { float kv = bf2f((ushort)afs2[j]); s += kv*kv; }
        s += __shfl_xor(s, 16); s += __shfl_xor(s, 32);
        if (l < 16) diag[128 + w*16 + l] = DN2H * s;
        mx = fmaxf(mx, s);
    }
#pragma unroll
    for (int off = 1; off < 64; off <<= 1) mx = fmaxf(mx, __shfl_xor(mx, off));
    if (l == 0) sm[w] = mx;
    __syncthreads();
    const float mloc = DN * sqrtf(fmaxf(fmaxf(sm[0], sm[1]), fmaxf(sm[2], sm[3])))
                     * pnorm[lidx];
    if (t == 0) mlp[bh*NSLOT + blk] = mloc;

    // ---- pass 2: E accumulate
    f32x4 cacc[2][2] = {};
    float ksacc[8] = {};
    float svacc = 0.f;
#pragma unroll
    for (int c = 0; c < 3; c++) {
        if (c*64 >= rows) break;
        bf16x8 af = (c == 0) ? afs0 : (c == 1) ? afs1 : afs2;
        const int nr = min(64, rows - c*64);
        const int rbase = g0 + c*64;
        f32x4 dd[8];
#pragma unroll
        for (int nt = 0; nt < 8; nt++)
            dd[nt] = __builtin_amdgcn_mfma_f32_16x16x32_bf16(af, pb[nt], z, 0, 0, 0);
        __syncthreads();   // prev-chunk kpsT/vt reads done
        float dg[4];
#pragma unroll
        for (int j = 0; j < 4; j++) dg[j] = diag[c*64 + w*16 + lq*4 + j];
#pragma unroll
        for (int nt = 0; nt < 8; nt++) {
            ushort4 kp4;
            ushort* kpp = (ushort*)&kp4;
#pragma unroll
            for (int j = 0; j < 4; j++) {
                int rj = w*16 + lq*4 + j;
                float e = 0.f;
                if (rj < nr) e = __expf(DN*dd[nt][j] - dg[j] - mloc);
                ksacc[nt] += e;
                kpp[j] = f2bf(e);
            }
            *(ushort4*)&kpsT[nt*16 + lr][w*16 + lq*4] = kp4;
        }
        for (int i = t; i < 512; i += 256) {
            int r = i >> 3, c4 = (i & 7) * 4;
            ushort4 vv = make_ushort4(0, 0, 0, 0);
            if (r < nr)
                vv = *(const ushort4*)(qkvb + (size_t)(rbase + r)*QKVS + 256 + h*32 + c4);
            vt[c4+0][r] = vv.x; vt[c4+1][r] = vv.y;
            vt[c4+2][r] = vv.z; vt[c4+3][r] = vv.w;
        }
        __syncthreads();   // kpsT + vt ready
        {
            int dh = t & 31, gs = (t >> 5) * 8;
            float p = 0.f;
#pragma unroll
            for (int i = 0; i < 8; i++) p += bf2f(vt[dh][gs + i]);
            svacc += p;
        }
#pragma unroll
        for (int ks = 0; ks < 2; ks++) {
            bf16x8 a0 = *(const bf16x8*)&vt[lr][ks*32 + lq*8];
            bf16x8 a1 = *(const bf16x8*)&vt[16 + lr][ks*32 + lq*8];
#pragma unroll
            for (int ntp = 0; ntp < 2; ntp++) {
                bf16x8 bfr = *(const bf16x8*)&kpsT[(w*2 + ntp)*16 + lr][ks*32 + lq*8];
                cacc[0][ntp] = __builtin_amdgcn_mfma_f32_16x16x32_bf16(a0, bfr, cacc[0][ntp], 0, 0, 0);
                cacc[1][ntp] = __builtin_amdgcn_mfma_f32_16x16x32_bf16(a1, bfr, cacc[1][ntp], 0, 0, 0);
            }
        }
    }
    // ---- slot stores (all plain)
    float* cslot = ctxp + (size_t)(bh*NSLOT + blk)*4096;
#pragma unroll
    for (int dt = 0; dt < 2; dt++)
#pragma unroll
        for (int ntp = 0; ntp < 2; ntp++)
#pragma unroll
            for (int j = 0; j < 4; j++)
                cslot[(dt*16 + lq*4 + j)*128 + (w*2 + ntp)*16 + lr] = cacc[dt][ntp][j];
#pragma unroll
    for (int nt = 0; nt < 8; nt++) {
        float v = ksacc[nt];
        v += __shfl_xor(v, 16); v += __shfl_xor(v, 32);
        if (l < 16) ksl[w][nt*16 + l] = v;
    }
    svl[t >> 5][t & 31] = svacc;
    __syncthreads();
    if (t < 128)
        ksp[(size_t)(bh*NSLOT + blk)*128 + t] = ksl[0][t] + ksl[1][t] + ksl[2][t] + ksl[3][t];
    if (t < 32) {
        float sv = 0.f;
#pragma unroll
        for (int i = 0; i < 8; i++) sv += svl[i][t];
        svp[(size_t)(bh*NSLOT + blk)*32 + t] = sv;
    }
}

// cred2: exact global-shift fixup -> ctx bf16, ksum fp32.  grid (16, 8*NBP)
__global__ __launch_bounds__(256) void k_cred2(const float* __restrict__ ctxp,
    const float* __restrict__ ksp, const float* __restrict__ svp,
    const float* __restrict__ mlp, ushort* __restrict__ ctxbg,
    float* __restrict__ ksum)
{
    __shared__ float mls[NSLOT];
    __shared__ float sc[NSLOT];
    __shared__ float svt[32];
    const int bh = blockIdx.y, blk = blockIdx.x, t = threadIdx.x;
    if (t < NSLOT) mls[t] = mlp[bh*NSLOT + t];
    __syncthreads();
    float km = -1e30f;
    for (int s = 0; s < NSLOT; s++) km = fmaxf(km, mls[s]);
    if (t < NSLOT) sc[t] = __expf(mls[t] - km);
    if (t < 32) {
        float sv = 0.f;
        for (int s = 0; s < NSLOT; s++) sv += svp[(size_t)(bh*NSLOT + s)*32 + t];
        svt[t] = sv;
    }
    __syncthreads();
    const int i = blk*256 + t;
    float acc = 0.f;
    for (int s = 0; s < NSLOT; s++)
        acc += sc[s] * ctxp[(size_t)(bh*NSLOT + s)*4096 + i];
    ctxbg[bh*4096 + i] = f2bf(RATIO * (acc + EPSK * svt[i >> 7]));
    if (blk == 0 && t < 128) {
        float ka = 0.f;
        for (int s = 0; s < NSLOT; s++)
            ka += sc[s] * ksp[(size_t)(bh*NSLOT + s)*128 + t];
        ksum[bh*128 + t] = RATIO * (ka + EPSK * (float)Gg);
    }
}

// attn: o = dinv * (qp @ ctx).  grid (NSLOT, 8*NBP)
__global__ __launch_bounds__(256) void k_attn(const ushort* __restrict__ qkv,
    const ushort* __restrict__ projb, const ushort* __restrict__ ctxbg,
    const float* __restrict__ ksum, ushort* __restrict__ obuf)
{
    __shared__ ushort qps[64][136];
    __shared__ float ksl[128];
    __shared__ float dgq[64];
    const int bh = blockIdx.y, blk = blockIdx.x;
    const int h = bh & 7;
    const ushort* qkvb = qkv + (size_t)(bh >> 3) * Gg * QKVS;
    ushort* obufb = obuf + (size_t)(bh >> 3) * Gg * 256;
    const int t = threadIdx.x, w = t >> 6, l = t & 63;
    const int lr = l & 15, lq = l >> 4;
    bf16x8 pb[8];
#pragma unroll
    for (int nt = 0; nt < 8; nt++)
        pb[nt] = *(const bf16x8*)(projb + (nt*16 + lr)*32 + lq*8);
    if (t < 128) ksl[t] = ksum[bh*128 + t];
    bf16x8 cb[2][4];
#pragma unroll
    for (int dt = 0; dt < 2; dt++)
#pragma unroll
        for (int ks = 0; ks < 4; ks++)
            cb[dt][ks] = *(const bf16x8*)(ctxbg + bh*4096 + (dt*16 + lr)*128 + ks*32 + lq*8);
    __syncthreads();
    const int g0 = blk * NBLK;
    const int rows = min(NBLK, Gg - g0);
    f32x4 z = {};
    for (int gc = 0; gc < rows; gc += 64) {
        const int nr = min(64, rows - gc);
        const int rbase = g0 + gc;
        int arow = min(rbase + w*16 + lr, Gg - 1);
        bf16x8 af = *(const bf16x8*)(qkvb + (size_t)arow*QKVS + 512 + h*32 + lq*8);
        float s = 0.f;
#pragma unroll
        for (int j = 0; j < 8; j++) { float qv = bf2f((ushort)af[j]); s += qv*qv; }
        s += __shfl_xor(s, 16); s += __shfl_xor(s, 32);
        if (l < 16) dgq[w*16 + l] = DN2H * s;
        f32x4 dd[8];
#pragma unroll
        for (int nt = 0; nt < 8; nt++)
            dd[nt] = __builtin_amdgcn_mfma_f32_16x16x32_bf16(af, pb[nt], z, 0, 0, 0);
        __syncthreads();   // dgq ready; prev-chunk qps reads done
        float dg[4], mq[4], den[4], dinv[4];
#pragma unroll
        for (int j = 0; j < 4; j++) {
            dg[j] = dgq[w*16 + lq*4 + j];
            float m = -1e30f;
#pragma unroll
            for (int nt = 0; nt < 8; nt++) m = fmaxf(m, dd[nt][j]);
            mq[j] = m;
        }
#pragma unroll
        for (int off = 1; off < 16; off <<= 1)
#pragma unroll
            for (int j = 0; j < 4; j++) mq[j] = fmaxf(mq[j], __shfl_xor(mq[j], off));
#pragma unroll
        for (int j = 0; j < 4; j++) { mq[j] = DN*mq[j]; den[j] = 0.f; }
#pragma unroll
        for (int nt = 0; nt < 8; nt++) {
            float kv = ksl[nt*16 + lr];
#pragma unroll
            for (int j = 0; j < 4; j++) {
                float p = RATIO * (__expf(DN*dd[nt][j] - dg[j] - mq[j]) + EPSK);
                dd[nt][j] = p;
                den[j] += p * kv;
            }
        }
#pragma unroll
        for (int off = 1; off < 16; off <<= 1)
#pragma unroll
            for (int j = 0; j < 4; j++) den[j] += __shfl_xor(den[j], off);
#pragma unroll
        for (int j = 0; j < 4; j++) dinv[j] = 1.f / den[j];
#pragma unroll
        for (int nt = 0; nt < 8; nt++)
#pragma unroll
            for (int j = 0; j < 4; j++)
                qps[w*16 + lq*4 + j][nt*16 + lr] = f2bf(dd[nt][j]);
        __syncthreads();
        f32x4 oacc[2] = {};
#pragma unroll
        for (int ks = 0; ks < 4; ks++) {
            bf16x8 aq = *(const bf16x8*)&qps[w*16 + lr][ks*32 + lq*8];
            oacc[0] = __builtin_amdgcn_mfma_f32_16x16x32_bf16(aq, cb[0][ks], oacc[0], 0, 0, 0);
            oacc[1] = __builtin_amdgcn_mfma_f32_16x16x32_bf16(aq, cb[1][ks], oacc[1], 0, 0, 0);
        }
#pragma unroll
        for (int dt = 0; dt < 2; dt++)
#pragma unroll
            for (int j = 0; j < 4; j++) {
                int rj = w*16 + lq*4 + j;
                if (rj < nr)
                    obufb[(size_t)(rbase + rj)*256 + h*32 + dt*16 + lr]
                        = f2bf(oacc[dt][j] * dinv[j]);
            }
    }
}

// ------------------------------------------------- head dot: out = relu(u.w2 + b2)
// 512 thr, 8 rows/block (1 wave per row), 16 bf16/lane.  grid ceil(M/8).
__global__ __launch_bounds__(512) void k_headd(const ushort* __restrict__ u,
    const float* __restrict__ w2, const float* __restrict__ b2,
    float* __restrict__ outp, int Mrows)
{
    const int w = threadIdx.x >> 6, l = threadIdx.x & 63;
    const int row = blockIdx.x * 8 + w;
    if (row >= Mrows) return;
    const ushort* up = u + (size_t)row * 1024 + l * 16;
    const float*  wp = w2 + l * 16;
    float acc = 0.f;
#pragma unroll
    for (int i = 0; i < 2; i++) {
        uint4 uv = *(const uint4*)(up + i*8);
        const ushort* us = (const ushort*)&uv;
        float4 w0 = *(const float4*)(wp + i*8);
        float4 w1 = *(const float4*)(wp + i*8 + 4);
        acc += bf2f(us[0])*w0.x + bf2f(us[1])*w0.y
             + bf2f(us[2])*w0.z + bf2f(us[3])*w0.w
             + bf2f(us[4])*w1.x + bf2f(us[5])*w1.y
             + bf2f(us[6])*w1.z + bf2f(us[7])*w1.w;
    }
#pragma unroll
    for (int off = 1; off < 64; off <<= 1) acc += __shfl_xor(acc, off);
    if (l == 0) outp[row] = fmaxf(acc + b2[0], 0.f);
}

// ---------------------------------------------------------------- launch
extern "C" void kernel_launch(void* const* d_in, const int* in_sizes, int n_in,
                              void* d_out, int out_size, void* d_ws, size_t ws_size,
                              hipStream_t stream)
{
    const float* x        = (const float*)d_in[0];
    const float* gene_emb = (const float*)d_in[1];
    const float* se_w1    = (const float*)d_in[2];
    const float* se_b1    = (const float*)d_in[3];
    const float* se_w2    = (const float*)d_in[4];
    const float* se_b2    = (const float*)d_in[5];
    const float* proj_b1  = (const float*)d_in[7];
    const float* proj_b2  = (const float*)d_in[9];
    const float* ln1_g    = (const float*)d_in[10];
    const float* ln1_b    = (const float*)d_in[11];
    const float* bo       = (const float*)d_in[16];
    const float* ln2_g    = (const float*)d_in[17];
    const float* ln2_b    = (const float*)d_in[18];
    const float* ff_b1    = (const float*)d_in[20];
    const float* ff_b2    = (const float*)d_in[22];
    const float* featp    = (const float*)d_in[23];
    const float* norm_g   = (const float*)d_in[24];
    const float* norm_b   = (const float*)d_in[25];
    const float* head_b1  = (const float*)d_in[27];
    const float* head_w2  = (const float*)d_in[28];
    const float* head_b2  = (const float*)d_in[29];
    const float* wq  = (const float*)d_in[12];
    const float* wk  = (const float*)d_in[13];
    const float* wv  = (const float*)d_in[14];
    const float* wo  = (const float*)d_in[15];
    const float* ff_w1 = (const float*)d_in[19];
    const float* ff_w2 = (const float*)d_in[21];
    const float* proj_w1 = (const float*)d_in[6];
    const float* proj_w2 = (const float*)d_in[8];
    const float* head_w1 = (const float*)d_in[26];
    float* out = (float*)d_out;

    // ---- adaptive multi-batch: NBP=2 needs ~172 MB; fallback NBP=1
    const int NBP  = (ws_size >= (size_t)185000000) ? 2 : 1;
    const int MB   = NBP * Gg;
    const int CHKF = (NBP == 2 && ws_size >= (size_t)210000000) ? 40000
                   : (NBP == 2 || ws_size >= (size_t)102000000) ? 20000 : 10000;
    const int NCHF = MB / CHKF;
    const int NPASS = Bb / NBP;

    float* w = (float*)d_ws;
    const size_t SBm = (size_t)MB * Dd;
    float* f_h  = w;                             // [MB,256] fp32 residual
    float* B1   = w + SBm;                       // [MB,256] fp32 y; attn slots alias
    float* samp = w + 2*SBm;                     // 2048
    float* t1   = samp + 2048;                   // 2048
    float* ksum = t1 + 2048;                     // NBP*1024
    ushort* ctxbg = (ushort*)(ksum + NBP*1024);  // NBP*8*4096 ushorts
    float* pnormb = (float*)(ctxbg + NBP*32768); // 4
    ushort* Ab  = (ushort*)(w + 2*SBm + 40000);  // [MB,256] bf16
    ushort* U   = Ab + SBm;                      // QKV [MB,768] | B4 [CHKF,1024]
    const size_t usz = (size_t)MB * QKVS > (size_t)CHKF * FFf
                     ? (size_t)MB * QKVS : (size_t)CHKF * FFf;
    ushort* Wt  = U + usz;                       // 3,932,160 bf16
    ushort* projb = Wt + 3932160;                // 16384 bf16
    ushort* QKVb = U;
    ushort* B4   = U;
    float* ctxp = B1;                            // NBP*NSLOT*8 x 4096
    float* ksp  = B1 + (size_t)NBP*NSLOT*8*4096;
    float* svp  = ksp + (size_t)NBP*NSLOT*8*128;
    float* mlp  = svp + (size_t)NBP*NSLOT*8*32;

    const size_t LW = 786432;
    ushort* pj1T = Wt + 4*LW;
    ushort* pj2T = pj1T + 262144;
    ushort* hd1T = pj2T + 262144;

    auto gemmb = [&](const ushort* A, const ushort* Bt, const float* bias,
                     ushort* C, int Mr, int N, int K, int act) {
        gemm_bf<<<dim3(N/128, (Mr + 127)/128), 512, 0, stream>>>(A, Bt, bias, C, Mr, N, K, act);
    };
    auto gemml = [&](const ushort* A, const ushort* Bt, const float* bias,
                     const float* res, float* Cout, ushort* ABout,
                     const float* g, const float* be, int Mr, int K, int addC) {
        gemm_ln<<<dim3((Mr + 63)/64), 512, 0, stream>>>(A, Bt, bias, res, Cout, ABout,
                                                        g, be, Mr, K, addC);
    };

    // ---- weight casts + proj norms + sample embedding (parallel split)
    k_wt4<<<dim3(8, 8, 16), 256, 0, stream>>>(wk, wv, wq, wo, Wt);
    k_wtA<<<dim3(32, 8, 6), 256, 0, stream>>>(ff_w1, proj_w1, head_w1, Wt);
    k_wtB<<<dim3(8, 32, 5), 256, 0, stream>>>(ff_w2, proj_w2, Wt);
    k_pcast<<<64, 256, 0, stream>>>(featp, projb, Ll*Mm*DHh);
    k_pn<<<4, 128, 0, stream>>>(featp, pnormb);
    k_zero<<<8, 256, 0, stream>>>(t1, 2048);
    k_se1<<<dim3(80, 8), 256, 0, stream>>>(x, se_w1, t1);
    k_se2<<<8, 256, 0, stream>>>(t1, se_b1, se_w2, se_b2, samp);

    // ---- per pass (NBP batches) full network
    for (int p = 0; p < NPASS; p++) {
        k_embed<<<MB/4, 256, 0, stream>>>(x, gene_emb, samp, Ab, p*NBP);
        for (int c = 0; c < NCHF; c++) {
            size_t off = (size_t)c * CHKF * Dd;
            gemmb(Ab + off, pj1T, proj_b1, B4, CHKF, FFf, Dd, 1);
            gemml(B4, pj2T, proj_b2, nullptr, f_h + off, Ab + off,
                  ln1_g, ln1_b, CHKF, FFf, 0);
        }
        for (int l = 0; l < Ll; l++) {
            ushort* lw = Wt + (size_t)l * LW;
            const ushort* qkvT = lw;
            const ushort* oT   = lw + 196608;
            const ushort* f1T  = lw + 262144;
            const ushort* f2T  = lw + 524288;
            const ushort* pjb  = projb + (size_t)l*Mm*DHh;
            const float* gn = (l < Ll-1) ? ln1_g + (l+1)*Dd : norm_g;
            const float* bn = (l < Ll-1) ? ln1_b + (l+1)*Dd : norm_b;

            gemmb(Ab, qkvT, nullptr, QKVb, MB, QKVS, Dd, 0);
            k_ctx2<<<dim3(NSLOT, 8*NBP), 256, 0, stream>>>(QKVb, pjb, pnormb, l,
                                                           ctxp, ksp, svp, mlp);
            k_cred2<<<dim3(16, 8*NBP), 256, 0, stream>>>(ctxp, ksp, svp, mlp,
                                                         ctxbg, ksum);
            k_attn<<<dim3(NSLOT, 8*NBP), 256, 0, stream>>>(QKVb, pjb, ctxbg, ksum, Ab);
            gemml(Ab, oT, bo + l*Dd, f_h, B1, Ab,
                  ln2_g + l*Dd, ln2_b + l*Dd, MB, Dd, 0);
            for (int c = 0; c < NCHF; c++) {
                size_t off = (size_t)c * CHKF * Dd;
                gemmb(Ab + off, f1T, ff_b1 + l*FFf, B4, CHKF, FFf, Dd, 2);
                gemml(B4, f2T, ff_b2 + l*Dd, B1 + off, f_h + off, Ab + off,
                      gn, bn, CHKF, FFf, 1);
            }
        }
        // head: u = relu(Ab@hd1 + b1) via proven gemm_bf, then lean dot kernel.
        gemmb(Ab, hd1T, head_b1, B4, MB, FFf, Dd, 1);
        k_headd<<<(MB + 7)/8, 512, 0, stream>>>(B4, head_w2, head_b2,
                                                out + (size_t)p*MB, MB);
    }
}

// Round 23
// 6094.302 us; speedup vs baseline: 1.0820x; 1.0820x over previous
//
#include <hip/hip_runtime.h>

// SimplePerformer forward: fused-LN bf16-MFMA GEMMs + 3-kernel exact FAVOR+.
// Round 23: exact revert to r21 (best: 6.105 ms).  gemm_ln = r17 optimum
// (BM=64/BK=64/43KB single-buffer); CHKF=40000; split head; merged embed.
// Pipelining ledger: r18 dbuf, r19 BM=128, r22 counted-vmcnt all refuted
// (occupancy loss > latency gain at this shape).
// B=8 G=20000 D=256 H=8 DH=32 L=4 M=128 FF=1024
#define Bb 8
#define Gg 20000
#define Dd 256
#define Hh 8
#define DHh 32
#define Ll 4
#define Mm 128
#define FFf 1024
#define QKVS 768   // fused qkv row stride: [k | v | q]
#define NBLK 192   // rows per attention block
#define NSLOT 105  // ceil(20000/192) blocks per head

typedef __attribute__((ext_vector_type(8))) short bf16x8;
typedef __attribute__((ext_vector_type(4))) float f32x4;

#define DN    0.4204482076268573f     /* 32^-0.25 */
#define DN2H  0.088388347648318447f   /* 0.5 * 32^-0.5 */
#define RATIO 0.08838834764831845f    /* 128^-0.5 */
#define EPSK  1e-4f

__device__ __forceinline__ float geluf(float x) {
    return 0.5f * x * (1.0f + erff(x * 0.70710678118654752f));
}
__device__ __forceinline__ float bf2f(ushort u) {
    union { uint i; float f; } v; v.i = ((uint)u) << 16; return v.f;
}
__device__ __forceinline__ ushort f2bf(float f) {
    union { float f; uint i; } v; v.f = f;
    uint i = v.i;
    return (ushort)((i + 0x7FFFu + ((i >> 16) & 1u)) >> 16);   // RNE
}
__device__ __forceinline__ void gload16(const void* g, void* l) {
    __builtin_amdgcn_global_load_lds(
        (const __attribute__((address_space(1))) void*)g,
        (__attribute__((address_space(3))) void*)l, 16, 0, 0);
}

// ------------------------------------------------- batched weight casts
__global__ __launch_bounds__(256) void k_wt4(const float* __restrict__ wk,
    const float* __restrict__ wv, const float* __restrict__ wq,
    const float* __restrict__ wo, ushort* __restrict__ Wt)
{
    const int z = blockIdx.z, l = z >> 2, wh = z & 3;
    const float* src = (wh == 0) ? wk : (wh == 1) ? wv : (wh == 2) ? wq : wo;
    src += (size_t)l * 65536;
    ushort* d = Wt + (size_t)l * 786432 + (size_t)wh * 65536;
    __shared__ float tl[32][33];
    const int n0 = blockIdx.x * 32, k0 = blockIdx.y * 32;
    const int tx = threadIdx.x & 31, ty = threadIdx.x >> 5;
#pragma unroll
    for (int i = 0; i < 4; i++)
        tl[ty + i*8][tx] = src[(size_t)(k0 + ty + i*8) * 256 + n0 + tx];
    __syncthreads();
#pragma unroll
    for (int i = 0; i < 4; i++)
        d[(size_t)(n0 + ty + i*8) * 256 + k0 + tx] = f2bf(tl[tx][ty + i*8]);
}

__global__ __launch_bounds__(256) void k_wtA(const float* __restrict__ ff1,
    const float* __restrict__ pw1, const float* __restrict__ hw1,
    ushort* __restrict__ Wt)
{
    const int z = blockIdx.z;
    const float* src; ushort* d;
    if (z < 4)      { src = ff1 + (size_t)z*262144; d = Wt + (size_t)z*786432 + 262144; }
    else if (z == 4){ src = pw1; d = Wt + (size_t)4*786432; }
    else            { src = hw1; d = Wt + (size_t)4*786432 + 524288; }
    __shared__ float tl[32][33];
    const int n0 = blockIdx.x * 32, k0 = blockIdx.y * 32;
    const int tx = threadIdx.x & 31, ty = threadIdx.x >> 5;
#pragma unroll
    for (int i = 0; i < 4; i++)
        tl[ty + i*8][tx] = src[(size_t)(k0 + ty + i*8) * 1024 + n0 + tx];
    __syncthreads();
#pragma unroll
    for (int i = 0; i < 4; i++)
        d[(size_t)(n0 + ty + i*8) * 256 + k0 + tx] = f2bf(tl[tx][ty + i*8]);
}

__global__ __launch_bounds__(256) void k_wtB(const float* __restrict__ ff2,
    const float* __restrict__ pw2, ushort* __restrict__ Wt)
{
    const int z = blockIdx.z;
    const float* src; ushort* d;
    if (z < 4) { src = ff2 + (size_t)z*262144; d = Wt + (size_t)z*786432 + 524288; }
    else       { src = pw2; d = Wt + (size_t)4*786432 + 262144; }
    __shared__ float tl[32][33];
    const int n0 = blockIdx.x * 32, k0 = blockIdx.y * 32;
    const int tx = threadIdx.x & 31, ty = threadIdx.x >> 5;
#pragma unroll
    for (int i = 0; i < 4; i++)
        tl[ty + i*8][tx] = src[(size_t)(k0 + ty + i*8) * 256 + n0 + tx];
    __syncthreads();
#pragma unroll
    for (int i = 0; i < 4; i++)
        d[(size_t)(n0 + ty + i*8) * 1024 + k0 + tx] = f2bf(tl[tx][ty + i*8]);
}

__global__ __launch_bounds__(256) void k_pcast(const float* __restrict__ src,
    ushort* __restrict__ dst, int n)
{
    int i = blockIdx.x*256 + threadIdx.x;
    if (i < n) dst[i] = f2bf(src[i]);
}

// pnorm[l] = max_m ||proj[l,m,:]||_2   grid (4), 128 thr
__global__ __launch_bounds__(128) void k_pn(const float* __restrict__ featp,
    float* __restrict__ pnorm)
{
    const int l = blockIdx.x, t = threadIdx.x;
    const float* p = featp + (size_t)l*4096 + t*32;
    float s = 0.f;
#pragma unroll
    for (int d = 0; d < 32; d++) s += p[d]*p[d];
#pragma unroll
    for (int off = 1; off < 64; off <<= 1) s = fmaxf(s, __shfl_xor(s, off));
    __shared__ float sm2[2];
    if ((t & 63) == 0) sm2[t >> 6] = s;
    __syncthreads();
    if (t == 0) pnorm[l] = sqrtf(fmaxf(sm2[0], sm2[1]));
}

// ------------------------------------------------- bf16 MFMA GEMM 128x128
// 512 thr (8 waves 2Mx4N, wave tile 64x32), BK=64, single-buffer 32KB LDS.
__global__ __launch_bounds__(512) void gemm_bf(
    const ushort* __restrict__ A, const ushort* __restrict__ Bt,
    const float* __restrict__ bias, ushort* __restrict__ C,
    int Mrows, int N, int K, int act)
{
    __shared__ ushort As[8192];   // [8 rg][2 kg][512]
    __shared__ ushort Bs[8192];
    const int t = threadIdx.x;
    const int l = t & 63, wid = t >> 6;        // 8 waves
    const int lr = l & 15, q = l >> 4;
    const int wm = wid >> 2, wn = wid & 3;     // 2 x 4 wave grid
    const int row0 = blockIdx.y * 128, col0 = blockIdx.x * 128;

    const int sar = min(row0 + wid*16 + lr, Mrows - 1);
    const ushort* gA = A  + (size_t)sar * K + q*8;
    const ushort* gB = Bt + (size_t)(col0 + wid*16 + lr) * K + q*8;
    ushort* lA = As + wid*1024;
    ushort* lB = Bs + wid*1024;

    f32x4 acc[4][2] = {};

    for (int k0 = 0; k0 < K; k0 += 64) {
        __syncthreads();               // prev-chunk reads done
        gload16(gA + k0,      lA);
        gload16(gA + k0 + 32, lA + 512);
        gload16(gB + k0,      lB);
        gload16(gB + k0 + 32, lB + 512);
        __syncthreads();               // stage complete
#pragma unroll
        for (int kg = 0; kg < 2; kg++) {
            bf16x8 af[4];
#pragma unroll
            for (int mi = 0; mi < 4; mi++)
                af[mi] = *(const bf16x8*)&As[((wm*4 + mi)*2 + kg)*512 + l*8];
#pragma unroll
            for (int ni = 0; ni < 2; ni++) {
                bf16x8 bv = *(const bf16x8*)&Bs[((wn*2 + ni)*2 + kg)*512 + l*8];
#pragma unroll
                for (int mi = 0; mi < 4; mi++)
                    acc[mi][ni] = __builtin_amdgcn_mfma_f32_16x16x32_bf16(
                        af[mi], bv, acc[mi][ni], 0, 0, 0);
            }
        }
    }

#pragma unroll
    for (int mi = 0; mi < 4; mi++)
#pragma unroll
        for (int j = 0; j < 4; j++) {
            int row = row0 + wm*64 + mi*16 + q*4 + j;
            if (row >= Mrows) continue;
#pragma unroll
            for (int ni = 0; ni < 2; ni++) {
                int col = col0 + wn*32 + ni*16 + lr;
                float v = acc[mi][ni][j];
                if (bias) v += bias[col];
                if (act == 1) v = fmaxf(v, 0.f);
                else if (act == 2) v = geluf(v);
                C[(size_t)row * N + col] = f2bf(v);
            }
        }
}

// ------------------------------------------------- GEMM + LayerNorm fusion
// v = A@Bt + bias [+res] [+Cout_old];  Cout=v (fp32);  ABout=LN(v) (bf16).
// 512 thr (8 waves 2Mx4N, wave tile 32x64), BM=64 BN=256 BK=64.  grid ceil(M/64)
__global__ __launch_bounds__(512) void gemm_ln(
    const ushort* __restrict__ A, const ushort* __restrict__ Bt,
    const float* __restrict__ bias, const float* __restrict__ res,
    float* __restrict__ Cout, ushort* __restrict__ ABout,
    const float* __restrict__ gam, const float* __restrict__ bet,
    int Mrows, int K, int addC)
{
    __shared__ ushort As[4096];    // 8 groups  (64 rows x 64 k)
    __shared__ ushort Bs[16384];   // 32 groups (256 cols x 64 k)
    __shared__ float red1[4][64], red2[4][64];
    const int t = threadIdx.x, l = t & 63, wid = t >> 6;
    const int lr = l & 15, lq = l >> 4;
    const int wm = wid >> 2, wn = wid & 3;     // 2 x 4 wave grid
    const int row0 = blockIdx.x * 64;

    // staging: wave wid fills A-group wid (rg=wid>>1, kg=wid&1) + B-groups wid*4..+3
    const int sar = min(row0 + (wid >> 1)*16 + lr, Mrows - 1);
    const ushort* gA = A + (size_t)sar * K + (wid & 1)*32 + lq*8;
    ushort* lA = As + wid*512;
    const ushort* gB[4];
    ushort* lB[4];
#pragma unroll
    for (int i = 0; i < 4; i++) {
        int g = wid*4 + i;
        gB[i] = Bt + (size_t)((g >> 1)*16 + lr) * K + (g & 1)*32 + lq*8;
        lB[i] = Bs + g*512;
    }

    f32x4 acc[2][4] = {};

    for (int k0 = 0; k0 < K; k0 += 64) {
        __syncthreads();               // prev-chunk reads done
        gload16(gA + k0, lA);
#pragma unroll
        for (int i = 0; i < 4; i++) gload16(gB[i] + k0, lB[i]);
        __syncthreads();               // stage complete
#pragma unroll
        for (int kg = 0; kg < 2; kg++) {
            bf16x8 af[2];
#pragma unroll
            for (int mi = 0; mi < 2; mi++)
                af[mi] = *(const bf16x8*)&As[((wm*2 + mi)*2 + kg)*512 + l*8];
#pragma unroll
            for (int ni = 0; ni < 4; ni++) {
                bf16x8 bv = *(const bf16x8*)&Bs[((wn*4 + ni)*2 + kg)*512 + l*8];
#pragma unroll
                for (int mi = 0; mi < 2; mi++)
                    acc[mi][ni] = __builtin_amdgcn_mfma_f32_16x16x32_bf16(
                        af[mi], bv, acc[mi][ni], 0, 0, 0);
            }
        }
    }

    // epilogue: bias/res/addC -> LN stats (cross-wave over wn) -> dual write
    float biasv[4], gv[4], bvv[4];
#pragma unroll
    for (int ni = 0; ni < 4; ni++) {
        int col = wn*64 + ni*16 + lr;
        biasv[ni] = bias[col]; gv[ni] = gam[col]; bvv[ni] = bet[col];
    }
#pragma unroll
    for (int mi = 0; mi < 2; mi++)
#pragma unroll
        for (int j = 0; j < 4; j++) {
            int row = row0 + wm*32 + mi*16 + lq*4 + j;
            bool ok = row < Mrows;
#pragma unroll
            for (int ni = 0; ni < 4; ni++) {
                float v = acc[mi][ni][j] + biasv[ni];
                size_t ci = (size_t)row * 256 + wn*64 + ni*16 + lr;
                if (ok) {
                    if (res)  v += res[ci];
                    if (addC) v += Cout[ci];
                }
                acc[mi][ni][j] = v;
            }
        }
#pragma unroll
    for (int mi = 0; mi < 2; mi++)
#pragma unroll
        for (int j = 0; j < 4; j++) {
            float s1 = 0.f, s2 = 0.f;
#pragma unroll
            for (int ni = 0; ni < 4; ni++) {
                float v = acc[mi][ni][j];
                s1 += v; s2 += v*v;
            }
#pragma unroll
            for (int off = 1; off < 16; off <<= 1) {
                s1 += __shfl_xor(s1, off);
                s2 += __shfl_xor(s2, off);
            }
            if (lr == 0) {
                int r = wm*32 + mi*16 + lq*4 + j;
                red1[wn][r] = s1;
                red2[wn][r] = s2;
            }
        }
    __syncthreads();
#pragma unroll
    for (int mi = 0; mi < 2; mi++)
#pragma unroll
        for (int j = 0; j < 4; j++) {
            int r = wm*32 + mi*16 + lq*4 + j;
            int row = row0 + r;
            if (row >= Mrows) continue;
            float m1 = (red1[0][r]+red1[1][r]+red1[2][r]+red1[3][r]) * (1.f/256.f);
            float m2 = (red2[0][r]+red2[1][r]+red2[2][r]+red2[3][r]) * (1.f/256.f);
            float inv = rsqrtf(m2 - m1*m1 + 1e-5f);
#pragma unroll
            for (int ni = 0; ni < 4; ni++) {
                size_t ci = (size_t)row * 256 + wn*64 + ni*16 + lr;
                float v = acc[mi][ni][j];
                Cout[ci] = v;
                ABout[ci] = f2bf((v - m1)*inv*gv[ni] + bvv[ni]);
            }
        }
}

// ------------------------------------------------- sample embedding (split)
__global__ __launch_bounds__(256) void k_zero(float* __restrict__ p, int n) {
    int i = blockIdx.x*256 + threadIdx.x;
    if (i < n) p[i] = 0.f;
}

__global__ __launch_bounds__(256) void k_se1(const float* __restrict__ x,
    const float* __restrict__ w1, float* __restrict__ t1)
{
    const int blk = blockIdx.x, b = blockIdx.y, t = threadIdx.x;
    const int k0 = blk * 250;
    float acc = 0.f;
    for (int kk = 0; kk < 250; kk++) {
        float xv = x[b*Gg + k0 + kk];
        acc += xv * w1[(size_t)(k0 + kk)*256 + t];
    }
    atomicAdd(&t1[b*256 + t], acc);
}

__global__ __launch_bounds__(256) void k_se2(const float* __restrict__ t1,
    const float* __restrict__ b1, const float* __restrict__ w2,
    const float* __restrict__ b2, float* __restrict__ samp)
{
    const int b = blockIdx.x, t = threadIdx.x;
    __shared__ float s1[256];
    s1[t] = fmaxf(t1[b*256 + t] + b1[t], 0.f);
    __syncthreads();
    float acc = 0.f;
    for (int n = 0; n < 256; n++) acc += s1[n] * w2[(size_t)n*256 + t];
    samp[b*256 + t] = acc + b2[t];
}

// embed: one wave per row, 4 cols/lane.  grid (MB/4); batch decoded from row.
__global__ __launch_bounds__(256) void k_embed(const float* __restrict__ x,
    const float* __restrict__ gene_emb, const float* __restrict__ samp,
    ushort* __restrict__ outb, int b0)
{
    const int w = threadIdx.x >> 6, l = threadIdx.x & 63;
    const int mb = blockIdx.x * 4 + w;          // row within this pass
    const int bb = mb / Gg;                     // 0..NBP-1
    const int g  = mb - bb * Gg;
    const int b  = b0 + bb;
    const float xv = x[b*Gg + g];
    const int d0 = l * 4;
    float4 gev = *(const float4*)&gene_emb[(size_t)g*256 + d0];
    float4 sv  = *(const float4*)&samp[b*256 + d0];
    float gv[4] = {gev.x, gev.y, gev.z, gev.w};
    float sp[4] = {sv.x, sv.y, sv.z, sv.w};
    ushort4 o;
    ushort* op = (ushort*)&o;
#pragma unroll
    for (int i = 0; i < 4; i++) {
        int d = d0 + i, j = d & 127;
        float ang = xv * __expf(-(float)j * 0.035977892078032f);   // ln(100)/128
        float ree = (d < 128) ? __sinf(ang) : __cosf(ang);
        if (xv == -10.0f) ree = 0.f;
        op[i] = f2bf(gv[i] + ree + sp[i]);
    }
    *(ushort4*)&outb[(size_t)mb*256 + d0] = o;
}

// ------------------------------------------------- FAVOR+ (3 kernels, exact)
// ctx2: norm-bound local shift + E-sums + Sv + slot stores.  grid (NSLOT, 8*NBP)
__global__ __launch_bounds__(256) void k_ctx2(const ushort* __restrict__ qkv,
    const ushort* __restrict__ projb, const float* __restrict__ pnorm, int lidx,
    float* __restrict__ ctxp, float* __restrict__ ksp, float* __restrict__ svp,
    float* __restrict__ mlp)
{
    __shared__ ushort kpsT[128][72];
    __shared__ ushort vt[32][72];
    __shared__ float diag[192];
    __shared__ float sm[4];
    __shared__ float ksl[4][128];
    __shared__ float svl[8][32];
    const int bh = blockIdx.y, blk = blockIdx.x;
    const int h = bh & 7;
    const ushort* qkvb = qkv + (size_t)(bh >> 3) * Gg * QKVS;
    const int t = threadIdx.x, w = t >> 6, l = t & 63;
    const int lr = l & 15, lq = l >> 4;
    bf16x8 pb[8];
#pragma unroll
    for (int nt = 0; nt < 8; nt++)
        pb[nt] = *(const bf16x8*)(projb + (nt*16 + lr)*32 + lq*8);
    const int g0 = blk * NBLK;
    const int rows = min(NBLK, Gg - g0);
    f32x4 z = {};

    // ---- pass 0: load k-frags, row norms -> diag LDS + block max norm
    bf16x8 afs0 = {}, afs1 = {}, afs2 = {};
    float mx = 0.f;
    {
        int arow = min(g0 + w*16 + lr, Gg - 1);
        afs0 = *(const bf16x8*)(qkvb + (size_t)arow*QKVS + h*32 + lq*8);
        float s = 0.f;
#pragma unroll
        for (int j = 0; j < 8; j++) { float kv = bf2f((ushort)afs0[j]); s += kv*kv; }
        s += __shfl_xor(s, 16); s += __shfl_xor(s, 32);
        if (l < 16) diag[w*16 + l] = DN2H * s;
        mx = fmaxf(mx, s);
    }
    if (64 < rows) {
        int arow = min(g0 + 64 + w*16 + lr, Gg - 1);
        afs1 = *(const bf16x8*)(qkvb + (size_t)arow*QKVS + h*32 + lq*8);
        float s = 0.f;
#pragma unroll
        for (int j = 0; j < 8; j++) { float kv = bf2f((ushort)afs1[j]); s += kv*kv; }
        s += __shfl_xor(s, 16); s += __shfl_xor(s, 32);
        if (l < 16) diag[64 + w*16 + l] = DN2H * s;
        mx = fmaxf(mx, s);
    }
    if (128 < rows) {
        int arow = min(g0 + 128 + w*16 + lr, Gg - 1);
        afs2 = *(const bf16x8*)(qkvb + (size_t)arow*QKVS + h*32 + lq*8);
        float s = 0.f;
#pragma unroll
        for (int j = 0; j < 8; j++) { float kv = bf2f((ushort)afs2[j]); s += kv*kv; }
        s += __shfl_xor(s, 16); s += __shfl_xor(s, 32);
        if (l < 16) diag[128 + w*16 + l] = DN2H * s;
        mx = fmaxf(mx, s);
    }
#pragma unroll
    for (int off = 1; off < 64; off <<= 1) mx = fmaxf(mx, __shfl_xor(mx, off));
    if (l == 0) sm[w] = mx;
    __syncthreads();
    const float mloc = DN * sqrtf(fmaxf(fmaxf(sm[0], sm[1]), fmaxf(sm[2], sm[3])))
                     * pnorm[lidx];
    if (t == 0) mlp[bh*NSLOT + blk] = mloc;

    // ---- pass 2: E accumulate
    f32x4 cacc[2][2] = {};
    float ksacc[8] = {};
    float svacc = 0.f;
#pragma unroll
    for (int c = 0; c < 3; c++) {
        if (c*64 >= rows) break;
        bf16x8 af = (c == 0) ? afs0 : (c == 1) ? afs1 : afs2;
        const int nr = min(64, rows - c*64);
        const int rbase = g0 + c*64;
        f32x4 dd[8];
#pragma unroll
        for (int nt = 0; nt < 8; nt++)
            dd[nt] = __builtin_amdgcn_mfma_f32_16x16x32_bf16(af, pb[nt], z, 0, 0, 0);
        __syncthreads();   // prev-chunk kpsT/vt reads done
        float dg[4];
#pragma unroll
        for (int j = 0; j < 4; j++) dg[j] = diag[c*64 + w*16 + lq*4 + j];
#pragma unroll
        for (int nt = 0; nt < 8; nt++) {
            ushort4 kp4;
            ushort* kpp = (ushort*)&kp4;
#pragma unroll
            for (int j = 0; j < 4; j++) {
                int rj = w*16 + lq*4 + j;
                float e = 0.f;
                if (rj < nr) e = __expf(DN*dd[nt][j] - dg[j] - mloc);
                ksacc[nt] += e;
                kpp[j] = f2bf(e);
            }
            *(ushort4*)&kpsT[nt*16 + lr][w*16 + lq*4] = kp4;
        }
        for (int i = t; i < 512; i += 256) {
            int r = i >> 3, c4 = (i & 7) * 4;
            ushort4 vv = make_ushort4(0, 0, 0, 0);
            if (r < nr)
                vv = *(const ushort4*)(qkvb + (size_t)(rbase + r)*QKVS + 256 + h*32 + c4);
            vt[c4+0][r] = vv.x; vt[c4+1][r] = vv.y;
            vt[c4+2][r] = vv.z; vt[c4+3][r] = vv.w;
        }
        __syncthreads();   // kpsT + vt ready
        {
            int dh = t & 31, gs = (t >> 5) * 8;
            float p = 0.f;
#pragma unroll
            for (int i = 0; i < 8; i++) p += bf2f(vt[dh][gs + i]);
            svacc += p;
        }
#pragma unroll
        for (int ks = 0; ks < 2; ks++) {
            bf16x8 a0 = *(const bf16x8*)&vt[lr][ks*32 + lq*8];
            bf16x8 a1 = *(const bf16x8*)&vt[16 + lr][ks*32 + lq*8];
#pragma unroll
            for (int ntp = 0; ntp < 2; ntp++) {
                bf16x8 bfr = *(const bf16x8*)&kpsT[(w*2 + ntp)*16 + lr][ks*32 + lq*8];
                cacc[0][ntp] = __builtin_amdgcn_mfma_f32_16x16x32_bf16(a0, bfr, cacc[0][ntp], 0, 0, 0);
                cacc[1][ntp] = __builtin_amdgcn_mfma_f32_16x16x32_bf16(a1, bfr, cacc[1][ntp], 0, 0, 0);
            }
        }
    }
    // ---- slot stores (all plain)
    float* cslot = ctxp + (size_t)(bh*NSLOT + blk)*4096;
#pragma unroll
    for (int dt = 0; dt < 2; dt++)
#pragma unroll
        for (int ntp = 0; ntp < 2; ntp++)
#pragma unroll
            for (int j = 0; j < 4; j++)
                cslot[(dt*16 + lq*4 + j)*128 + (w*2 + ntp)*16 + lr] = cacc[dt][ntp][j];
#pragma unroll
    for (int nt = 0; nt < 8; nt++) {
        float v = ksacc[nt];
        v += __shfl_xor(v, 16); v += __shfl_xor(v, 32);
        if (l < 16) ksl[w][nt*16 + l] = v;
    }
    svl[t >> 5][t & 31] = svacc;
    __syncthreads();
    if (t < 128)
        ksp[(size_t)(bh*NSLOT + blk)*128 + t] = ksl[0][t] + ksl[1][t] + ksl[2][t] + ksl[3][t];
    if (t < 32) {
        float sv = 0.f;
#pragma unroll
        for (int i = 0; i < 8; i++) sv += svl[i][t];
        svp[(size_t)(bh*NSLOT + blk)*32 + t] = sv;
    }
}

// cred2: exact global-shift fixup -> ctx bf16, ksum fp32.  grid (16, 8*NBP)
__global__ __launch_bounds__(256) void k_cred2(const float* __restrict__ ctxp,
    const float* __restrict__ ksp, const float* __restrict__ svp,
    const float* __restrict__ mlp, ushort* __restrict__ ctxbg,
    float* __restrict__ ksum)
{
    __shared__ float mls[NSLOT];
    __shared__ float sc[NSLOT];
    __shared__ float svt[32];
    const int bh = blockIdx.y, blk = blockIdx.x, t = threadIdx.x;
    if (t < NSLOT) mls[t] = mlp[bh*NSLOT + t];
    __syncthreads();
    float km = -1e30f;
    for (int s = 0; s < NSLOT; s++) km = fmaxf(km, mls[s]);
    if (t < NSLOT) sc[t] = __expf(mls[t] - km);
    if (t < 32) {
        float sv = 0.f;
        for (int s = 0; s < NSLOT; s++) sv += svp[(size_t)(bh*NSLOT + s)*32 + t];
        svt[t] = sv;
    }
    __syncthreads();
    const int i = blk*256 + t;
    float acc = 0.f;
    for (int s = 0; s < NSLOT; s++)
        acc += sc[s] * ctxp[(size_t)(bh*NSLOT + s)*4096 + i];
    ctxbg[bh*4096 + i] = f2bf(RATIO * (acc + EPSK * svt[i >> 7]));
    if (blk == 0 && t < 128) {
        float ka = 0.f;
        for (int s = 0; s < NSLOT; s++)
            ka += sc[s] * ksp[(size_t)(bh*NSLOT + s)*128 + t];
        ksum[bh*128 + t] = RATIO * (ka + EPSK * (float)Gg);
    }
}

// attn: o = dinv * (qp @ ctx).  grid (NSLOT, 8*NBP)
__global__ __launch_bounds__(256) void k_attn(const ushort* __restrict__ qkv,
    const ushort* __restrict__ projb, const ushort* __restrict__ ctxbg,
    const float* __restrict__ ksum, ushort* __restrict__ obuf)
{
    __shared__ ushort qps[64][136];
    __shared__ float ksl[128];
    __shared__ float dgq[64];
    const int bh = blockIdx.y, blk = blockIdx.x;
    const int h = bh & 7;
    const ushort* qkvb = qkv + (size_t)(bh >> 3) * Gg * QKVS;
    ushort* obufb = obuf + (size_t)(bh >> 3) * Gg * 256;
    const int t = threadIdx.x, w = t >> 6, l = t & 63;
    const int lr = l & 15, lq = l >> 4;
    bf16x8 pb[8];
#pragma unroll
    for (int nt = 0; nt < 8; nt++)
        pb[nt] = *(const bf16x8*)(projb + (nt*16 + lr)*32 + lq*8);
    if (t < 128) ksl[t] = ksum[bh*128 + t];
    bf16x8 cb[2][4];
#pragma unroll
    for (int dt = 0; dt < 2; dt++)
#pragma unroll
        for (int ks = 0; ks < 4; ks++)
            cb[dt][ks] = *(const bf16x8*)(ctxbg + bh*4096 + (dt*16 + lr)*128 + ks*32 + lq*8);
    __syncthreads();
    const int g0 = blk * NBLK;
    const int rows = min(NBLK, Gg - g0);
    f32x4 z = {};
    for (int gc = 0; gc < rows; gc += 64) {
        const int nr = min(64, rows - gc);
        const int rbase = g0 + gc;
        int arow = min(rbase + w*16 + lr, Gg - 1);
        bf16x8 af = *(const bf16x8*)(qkvb + (size_t)arow*QKVS + 512 + h*32 + lq*8);
        float s = 0.f;
#pragma unroll
        for (int j = 0; j < 8; j++) { float qv = bf2f((ushort)af[j]); s += qv*qv; }
        s += __shfl_xor(s, 16); s += __shfl_xor(s, 32);
        if (l < 16) dgq[w*16 + l] = DN2H * s;
        f32x4 dd[8];
#pragma unroll
        for (int nt = 0; nt < 8; nt++)
            dd[nt] = __builtin_amdgcn_mfma_f32_16x16x32_bf16(af, pb[nt], z, 0, 0, 0);
        __syncthreads();   // dgq ready; prev-chunk qps reads done
        float dg[4], mq[4], den[4], dinv[4];
#pragma unroll
        for (int j = 0; j < 4; j++) {
            dg[j] = dgq[w*16 + lq*4 + j];
            float m = -1e30f;
#pragma unroll
            for (int nt = 0; nt < 8; nt++) m = fmaxf(m, dd[nt][j]);
            mq[j] = m;
        }
#pragma unroll
        for (int off = 1; off < 16; off <<= 1)
#pragma unroll
            for (int j = 0; j < 4; j++) mq[j] = fmaxf(mq[j], __shfl_xor(mq[j], off));
#pragma unroll
        for (int j = 0; j < 4; j++) { mq[j] = DN*mq[j]; den[j] = 0.f; }
#pragma unroll
        for (int nt = 0; nt < 8; nt++) {
            float kv = ksl[nt*16 + lr];
#pragma unroll
            for (int j = 0; j < 4; j++) {
                float p = RATIO * (__expf(DN*dd[nt][j] - dg[j] - mq[j]) + EPSK);
                dd[nt][j] = p;
                den[j] += p * kv;
            }
        }
#pragma unroll
        for (int off = 1; off < 16; off <<= 1)
#pragma unroll
            for (int j = 0; j < 4; j++) den[j] += __shfl_xor(den[j], off);
#pragma unroll
        for (int j = 0; j < 4; j++) dinv[j] = 1.f / den[j];
#pragma unroll
        for (int nt = 0; nt < 8; nt++)
#pragma unroll
            for (int j = 0; j < 4; j++)
                qps[w*16 + lq*4 + j][nt*16 + lr] = f2bf(dd[nt][j]);
        __syncthreads();
        f32x4 oacc[2] = {};
#pragma unroll
        for (int ks = 0; ks < 4; ks++) {
            bf16x8 aq = *(const bf16x8*)&qps[w*16 + lr][ks*32 + lq*8];
            oacc[0] = __builtin_amdgcn_mfma_f32_16x16x32_bf16(aq, cb[0][ks], oacc[0], 0, 0, 0);
            oacc[1] = __builtin_amdgcn_mfma_f32_16x16x32_bf16(aq, cb[1][ks], oacc[1], 0, 0, 0);
        }
#pragma unroll
        for (int dt = 0; dt < 2; dt++)
#pragma unroll
            for (int j = 0; j < 4; j++) {
                int rj = w*16 + lq*4 + j;
                if (rj < nr)
                    obufb[(size_t)(rbase + rj)*256 + h*32 + dt*16 + lr]
                        = f2bf(oacc[dt][j] * dinv[j]);
            }
    }
}

// ------------------------------------------------- head dot: out = relu(u.w2 + b2)
// 512 thr, 8 rows/block (1 wave per row), 16 bf16/lane.  grid ceil(M/8).
__global__ __launch_bounds__(512) void k_headd(const ushort* __restrict__ u,
    const float* __restrict__ w2, const float* __restrict__ b2,
    float* __restrict__ outp, int Mrows)
{
    const int w = threadIdx.x >> 6, l = threadIdx.x & 63;
    const int row = blockIdx.x * 8 + w;
    if (row >= Mrows) return;
    const ushort* up = u + (size_t)row * 1024 + l * 16;
    const float*  wp = w2 + l * 16;
    float acc = 0.f;
#pragma unroll
    for (int i = 0; i < 2; i++) {
        uint4 uv = *(const uint4*)(up + i*8);
        const ushort* us = (const ushort*)&uv;
        float4 w0 = *(const float4*)(wp + i*8);
        float4 w1 = *(const float4*)(wp + i*8 + 4);
        acc += bf2f(us[0])*w0.x + bf2f(us[1])*w0.y
             + bf2f(us[2])*w0.z + bf2f(us[3])*w0.w
             + bf2f(us[4])*w1.x + bf2f(us[5])*w1.y
             + bf2f(us[6])*w1.z + bf2f(us[7])*w1.w;
    }
#pragma unroll
    for (int off = 1; off < 64; off <<= 1) acc += __shfl_xor(acc, off);
    if (l == 0) outp[row] = fmaxf(acc + b2[0], 0.f);
}

// ---------------------------------------------------------------- launch
extern "C" void kernel_launch(void* const* d_in, const int* in_sizes, int n_in,
                              void* d_out, int out_size, void* d_ws, size_t ws_size,
                              hipStream_t stream)
{
    const float* x        = (const float*)d_in[0];
    const float* gene_emb = (const float*)d_in[1];
    const float* se_w1    = (const float*)d_in[2];
    const float* se_b1    = (const float*)d_in[3];
    const float* se_w2    = (const float*)d_in[4];
    const float* se_b2    = (const float*)d_in[5];
    const float* proj_b1  = (const float*)d_in[7];
    const float* proj_b2  = (const float*)d_in[9];
    const float* ln1_g    = (const float*)d_in[10];
    const float* ln1_b    = (const float*)d_in[11];
    const float* bo       = (const float*)d_in[16];
    const float* ln2_g    = (const float*)d_in[17];
    const float* ln2_b    = (const float*)d_in[18];
    const float* ff_b1    = (const float*)d_in[20];
    const float* ff_b2    = (const float*)d_in[22];
    const float* featp    = (const float*)d_in[23];
    const float* norm_g   = (const float*)d_in[24];
    const float* norm_b   = (const float*)d_in[25];
    const float* head_b1  = (const float*)d_in[27];
    const float* head_w2  = (const float*)d_in[28];
    const float* head_b2  = (const float*)d_in[29];
    const float* wq  = (const float*)d_in[12];
    const float* wk  = (const float*)d_in[13];
    const float* wv  = (const float*)d_in[14];
    const float* wo  = (const float*)d_in[15];
    const float* ff_w1 = (const float*)d_in[19];
    const float* ff_w2 = (const float*)d_in[21];
    const float* proj_w1 = (const float*)d_in[6];
    const float* proj_w2 = (const float*)d_in[8];
    const float* head_w1 = (const float*)d_in[26];
    float* out = (float*)d_out;

    // ---- adaptive multi-batch: NBP=2 needs ~172 MB; fallback NBP=1
    const int NBP  = (ws_size >= (size_t)185000000) ? 2 : 1;
    const int MB   = NBP * Gg;
    const int CHKF = (NBP == 2 && ws_size >= (size_t)210000000) ? 40000
                   : (NBP == 2 || ws_size >= (size_t)102000000) ? 20000 : 10000;
    const int NCHF = MB / CHKF;
    const int NPASS = Bb / NBP;

    float* w = (float*)d_ws;
    const size_t SBm = (size_t)MB * Dd;
    float* f_h  = w;                             // [MB,256] fp32 residual
    float* B1   = w + SBm;                       // [MB,256] fp32 y; attn slots alias
    float* samp = w + 2*SBm;                     // 2048
    float* t1   = samp + 2048;                   // 2048
    float* ksum = t1 + 2048;                     // NBP*1024
    ushort* ctxbg = (ushort*)(ksum + NBP*1024);  // NBP*8*4096 ushorts
    float* pnormb = (float*)(ctxbg + NBP*32768); // 4
    ushort* Ab  = (ushort*)(w + 2*SBm + 40000);  // [MB,256] bf16
    ushort* U   = Ab + SBm;                      // QKV [MB,768] | B4 [CHKF,1024]
    const size_t usz = (size_t)MB * QKVS > (size_t)CHKF * FFf
                     ? (size_t)MB * QKVS : (size_t)CHKF * FFf;
    ushort* Wt  = U + usz;                       // 3,932,160 bf16
    ushort* projb = Wt + 3932160;                // 16384 bf16
    ushort* QKVb = U;
    ushort* B4   = U;
    float* ctxp = B1;                            // NBP*NSLOT*8 x 4096
    float* ksp  = B1 + (size_t)NBP*NSLOT*8*4096;
    float* svp  = ksp + (size_t)NBP*NSLOT*8*128;
    float* mlp  = svp + (size_t)NBP*NSLOT*8*32;

    const size_t LW = 786432;
    ushort* pj1T = Wt + 4*LW;
    ushort* pj2T = pj1T + 262144;
    ushort* hd1T = pj2T + 262144;

    auto gemmb = [&](const ushort* A, const ushort* Bt, const float* bias,
                     ushort* C, int Mr, int N, int K, int act) {
        gemm_bf<<<dim3(N/128, (Mr + 127)/128), 512, 0, stream>>>(A, Bt, bias, C, Mr, N, K, act);
    };
    auto gemml = [&](const ushort* A, const ushort* Bt, const float* bias,
                     const float* res, float* Cout, ushort* ABout,
                     const float* g, const float* be, int Mr, int K, int addC) {
        gemm_ln<<<dim3((Mr + 63)/64), 512, 0, stream>>>(A, Bt, bias, res, Cout, ABout,
                                                        g, be, Mr, K, addC);
    };

    // ---- weight casts + proj norms + sample embedding (parallel split)
    k_wt4<<<dim3(8, 8, 16), 256, 0, stream>>>(wk, wv, wq, wo, Wt);
    k_wtA<<<dim3(32, 8, 6), 256, 0, stream>>>(ff_w1, proj_w1, head_w1, Wt);
    k_wtB<<<dim3(8, 32, 5), 256, 0, stream>>>(ff_w2, proj_w2, Wt);
    k_pcast<<<64, 256, 0, stream>>>(featp, projb, Ll*Mm*DHh);
    k_pn<<<4, 128, 0, stream>>>(featp, pnormb);
    k_zero<<<8, 256, 0, stream>>>(t1, 2048);
    k_se1<<<dim3(80, 8), 256, 0, stream>>>(x, se_w1, t1);
    k_se2<<<8, 256, 0, stream>>>(t1, se_b1, se_w2, se_b2, samp);

    // ---- per pass (NBP batches) full network
    for (int p = 0; p < NPASS; p++) {
        k_embed<<<MB/4, 256, 0, stream>>>(x, gene_emb, samp, Ab, p*NBP);
        for (int c = 0; c < NCHF; c++) {
            size_t off = (size_t)c * CHKF * Dd;
            gemmb(Ab + off, pj1T, proj_b1, B4, CHKF, FFf, Dd, 1);
            gemml(B4, pj2T, proj_b2, nullptr, f_h + off, Ab + off,
                  ln1_g, ln1_b, CHKF, FFf, 0);
        }
        for (int l = 0; l < Ll; l++) {
            ushort* lw = Wt + (size_t)l * LW;
            const ushort* qkvT = lw;
            const ushort* oT   = lw + 196608;
            const ushort* f1T  = lw + 262144;
            const ushort* f2T  = lw + 524288;
            const ushort* pjb  = projb + (size_t)l*Mm*DHh;
            const float* gn = (l < Ll-1) ? ln1_g + (l+1)*Dd : norm_g;
            const float* bn = (l < Ll-1) ? ln1_b + (l+1)*Dd : norm_b;

            gemmb(Ab, qkvT, nullptr, QKVb, MB, QKVS, Dd, 0);
            k_ctx2<<<dim3(NSLOT, 8*NBP), 256, 0, stream>>>(QKVb, pjb, pnormb, l,
                                                           ctxp, ksp, svp, mlp);
            k_cred2<<<dim3(16, 8*NBP), 256, 0, stream>>>(ctxp, ksp, svp, mlp,
                                                         ctxbg, ksum);
            k_attn<<<dim3(NSLOT, 8*NBP), 256, 0, stream>>>(QKVb, pjb, ctxbg, ksum, Ab);
            gemml(Ab, oT, bo + l*Dd, f_h, B1, Ab,
                  ln2_g + l*Dd, ln2_b + l*Dd, MB, Dd, 0);
            for (int c = 0; c < NCHF; c++) {
                size_t off = (size_t)c * CHKF * Dd;
                gemmb(Ab + off, f1T, ff_b1 + l*FFf, B4, CHKF, FFf, Dd, 2);
                gemml(B4, f2T, ff_b2 + l*Dd, B1 + off, f_h + off, Ab + off,
                      gn, bn, CHKF, FFf, 1);
            }
        }
        // head: u = relu(Ab@hd1 + b1) via proven gemm_bf, then lean dot kernel.
        gemmb(Ab, hd1T, head_b1, B4, MB, FFf, Dd, 1);
        k_headd<<<(MB + 7)/8, 512, 0, stream>>>(B4, head_w2, head_b2,
                                                out + (size_t)p*MB, MB);
    }
}

// Round 24
// 6088.086 us; speedup vs baseline: 1.0831x; 1.0010x over previous
//
#include <hip/hip_runtime.h>

// SimplePerformer forward: fused-LN bf16-MFMA GEMMs + 3-kernel exact FAVOR+.
// Round 24: gated NBP=4 (2 passes x 4 batches, needs ws>=380MB; falls back to
// r23's NBP=2 otherwise) + gemm_ln LDS 43008->40960 (red aliases As) so
// exactly 4 blocks/CU fit when grids exceed 768 blocks.
// Ledger: r18 dbuf, r19 BM=128, r22 counted-vmcnt refuted (occupancy cliffs).
// B=8 G=20000 D=256 H=8 DH=32 L=4 M=128 FF=1024
#define Bb 8
#define Gg 20000
#define Dd 256
#define Hh 8
#define DHh 32
#define Ll 4
#define Mm 128
#define FFf 1024
#define QKVS 768   // fused qkv row stride: [k | v | q]
#define NBLK 192   // rows per attention block
#define NSLOT 105  // ceil(20000/192) blocks per head

typedef __attribute__((ext_vector_type(8))) short bf16x8;
typedef __attribute__((ext_vector_type(4))) float f32x4;

#define DN    0.4204482076268573f     /* 32^-0.25 */
#define DN2H  0.088388347648318447f   /* 0.5 * 32^-0.5 */
#define RATIO 0.08838834764831845f    /* 128^-0.5 */
#define EPSK  1e-4f

__device__ __forceinline__ float geluf(float x) {
    return 0.5f * x * (1.0f + erff(x * 0.70710678118654752f));
}
__device__ __forceinline__ float bf2f(ushort u) {
    union { uint i; float f; } v; v.i = ((uint)u) << 16; return v.f;
}
__device__ __forceinline__ ushort f2bf(float f) {
    union { float f; uint i; } v; v.f = f;
    uint i = v.i;
    return (ushort)((i + 0x7FFFu + ((i >> 16) & 1u)) >> 16);   // RNE
}
__device__ __forceinline__ void gload16(const void* g, void* l) {
    __builtin_amdgcn_global_load_lds(
        (const __attribute__((address_space(1))) void*)g,
        (__attribute__((address_space(3))) void*)l, 16, 0, 0);
}

// ------------------------------------------------- batched weight casts
__global__ __launch_bounds__(256) void k_wt4(const float* __restrict__ wk,
    const float* __restrict__ wv, const float* __restrict__ wq,
    const float* __restrict__ wo, ushort* __restrict__ Wt)
{
    const int z = blockIdx.z, l = z >> 2, wh = z & 3;
    const float* src = (wh == 0) ? wk : (wh == 1) ? wv : (wh == 2) ? wq : wo;
    src += (size_t)l * 65536;
    ushort* d = Wt + (size_t)l * 786432 + (size_t)wh * 65536;
    __shared__ float tl[32][33];
    const int n0 = blockIdx.x * 32, k0 = blockIdx.y * 32;
    const int tx = threadIdx.x & 31, ty = threadIdx.x >> 5;
#pragma unroll
    for (int i = 0; i < 4; i++)
        tl[ty + i*8][tx] = src[(size_t)(k0 + ty + i*8) * 256 + n0 + tx];
    __syncthreads();
#pragma unroll
    for (int i = 0; i < 4; i++)
        d[(size_t)(n0 + ty + i*8) * 256 + k0 + tx] = f2bf(tl[tx][ty + i*8]);
}

__global__ __launch_bounds__(256) void k_wtA(const float* __restrict__ ff1,
    const float* __restrict__ pw1, const float* __restrict__ hw1,
    ushort* __restrict__ Wt)
{
    const int z = blockIdx.z;
    const float* src; ushort* d;
    if (z < 4)      { src = ff1 + (size_t)z*262144; d = Wt + (size_t)z*786432 + 262144; }
    else if (z == 4){ src = pw1; d = Wt + (size_t)4*786432; }
    else            { src = hw1; d = Wt + (size_t)4*786432 + 524288; }
    __shared__ float tl[32][33];
    const int n0 = blockIdx.x * 32, k0 = blockIdx.y * 32;
    const int tx = threadIdx.x & 31, ty = threadIdx.x >> 5;
#pragma unroll
    for (int i = 0; i < 4; i++)
        tl[ty + i*8][tx] = src[(size_t)(k0 + ty + i*8) * 1024 + n0 + tx];
    __syncthreads();
#pragma unroll
    for (int i = 0; i < 4; i++)
        d[(size_t)(n0 + ty + i*8) * 256 + k0 + tx] = f2bf(tl[tx][ty + i*8]);
}

__global__ __launch_bounds__(256) void k_wtB(const float* __restrict__ ff2,
    const float* __restrict__ pw2, ushort* __restrict__ Wt)
{
    const int z = blockIdx.z;
    const float* src; ushort* d;
    if (z < 4) { src = ff2 + (size_t)z*262144; d = Wt + (size_t)z*786432 + 524288; }
    else       { src = pw2; d = Wt + (size_t)4*786432 + 262144; }
    __shared__ float tl[32][33];
    const int n0 = blockIdx.x * 32, k0 = blockIdx.y * 32;
    const int tx = threadIdx.x & 31, ty = threadIdx.x >> 5;
#pragma unroll
    for (int i = 0; i < 4; i++)
        tl[ty + i*8][tx] = src[(size_t)(k0 + ty + i*8) * 256 + n0 + tx];
    __syncthreads();
#pragma unroll
    for (int i = 0; i < 4; i++)
        d[(size_t)(n0 + ty + i*8) * 1024 + k0 + tx] = f2bf(tl[tx][ty + i*8]);
}

__global__ __launch_bounds__(256) void k_pcast(const float* __restrict__ src,
    ushort* __restrict__ dst, int n)
{
    int i = blockIdx.x*256 + threadIdx.x;
    if (i < n) dst[i] = f2bf(src[i]);
}

// pnorm[l] = max_m ||proj[l,m,:]||_2   grid (4), 128 thr
__global__ __launch_bounds__(128) void k_pn(const float* __restrict__ featp,
    float* __restrict__ pnorm)
{
    const int l = blockIdx.x, t = threadIdx.x;
    const float* p = featp + (size_t)l*4096 + t*32;
    float s = 0.f;
#pragma unroll
    for (int d = 0; d < 32; d++) s += p[d]*p[d];
#pragma unroll
    for (int off = 1; off < 64; off <<= 1) s = fmaxf(s, __shfl_xor(s, off));
    __shared__ float sm2[2];
    if ((t & 63) == 0) sm2[t >> 6] = s;
    __syncthreads();
    if (t == 0) pnorm[l] = sqrtf(fmaxf(sm2[0], sm2[1]));
}

// ------------------------------------------------- bf16 MFMA GEMM 128x128
// 512 thr (8 waves 2Mx4N, wave tile 64x32), BK=64, single-buffer 32KB LDS.
__global__ __launch_bounds__(512) void gemm_bf(
    const ushort* __restrict__ A, const ushort* __restrict__ Bt,
    const float* __restrict__ bias, ushort* __restrict__ C,
    int Mrows, int N, int K, int act)
{
    __shared__ ushort As[8192];   // [8 rg][2 kg][512]
    __shared__ ushort Bs[8192];
    const int t = threadIdx.x;
    const int l = t & 63, wid = t >> 6;        // 8 waves
    const int lr = l & 15, q = l >> 4;
    const int wm = wid >> 2, wn = wid & 3;     // 2 x 4 wave grid
    const int row0 = blockIdx.y * 128, col0 = blockIdx.x * 128;

    const int sar = min(row0 + wid*16 + lr, Mrows - 1);
    const ushort* gA = A  + (size_t)sar * K + q*8;
    const ushort* gB = Bt + (size_t)(col0 + wid*16 + lr) * K + q*8;
    ushort* lA = As + wid*1024;
    ushort* lB = Bs + wid*1024;

    f32x4 acc[4][2] = {};

    for (int k0 = 0; k0 < K; k0 += 64) {
        __syncthreads();               // prev-chunk reads done
        gload16(gA + k0,      lA);
        gload16(gA + k0 + 32, lA + 512);
        gload16(gB + k0,      lB);
        gload16(gB + k0 + 32, lB + 512);
        __syncthreads();               // stage complete
#pragma unroll
        for (int kg = 0; kg < 2; kg++) {
            bf16x8 af[4];
#pragma unroll
            for (int mi = 0; mi < 4; mi++)
                af[mi] = *(const bf16x8*)&As[((wm*4 + mi)*2 + kg)*512 + l*8];
#pragma unroll
            for (int ni = 0; ni < 2; ni++) {
                bf16x8 bv = *(const bf16x8*)&Bs[((wn*2 + ni)*2 + kg)*512 + l*8];
#pragma unroll
                for (int mi = 0; mi < 4; mi++)
                    acc[mi][ni] = __builtin_amdgcn_mfma_f32_16x16x32_bf16(
                        af[mi], bv, acc[mi][ni], 0, 0, 0);
            }
        }
    }

#pragma unroll
    for (int mi = 0; mi < 4; mi++)
#pragma unroll
        for (int j = 0; j < 4; j++) {
            int row = row0 + wm*64 + mi*16 + q*4 + j;
            if (row >= Mrows) continue;
#pragma unroll
            for (int ni = 0; ni < 2; ni++) {
                int col = col0 + wn*32 + ni*16 + lr;
                float v = acc[mi][ni][j];
                if (bias) v += bias[col];
                if (act == 1) v = fmaxf(v, 0.f);
                else if (act == 2) v = geluf(v);
                C[(size_t)row * N + col] = f2bf(v);
            }
        }
}

// ------------------------------------------------- GEMM + LayerNorm fusion
// v = A@Bt + bias [+res] [+Cout_old];  Cout=v (fp32);  ABout=LN(v) (bf16).
// 512 thr (8 waves 2Mx4N, wave tile 32x64), BM=64 BN=256 BK=64.  grid ceil(M/64)
// LDS 40960 B (red aliases dead As) -> exactly 4 blocks/CU.
__global__ __launch_bounds__(512) void gemm_ln(
    const ushort* __restrict__ A, const ushort* __restrict__ Bt,
    const float* __restrict__ bias, const float* __restrict__ res,
    float* __restrict__ Cout, ushort* __restrict__ ABout,
    const float* __restrict__ gam, const float* __restrict__ bet,
    int Mrows, int K, int addC)
{
    __shared__ ushort As[4096];    // 8 groups  (64 rows x 64 k)
    __shared__ ushort Bs[16384];   // 32 groups (256 cols x 64 k)
    const int t = threadIdx.x, l = t & 63, wid = t >> 6;
    const int lr = l & 15, lq = l >> 4;
    const int wm = wid >> 2, wn = wid & 3;     // 2 x 4 wave grid
    const int row0 = blockIdx.x * 64;

    // staging: wave wid fills A-group wid (rg=wid>>1, kg=wid&1) + B-groups wid*4..+3
    const int sar = min(row0 + (wid >> 1)*16 + lr, Mrows - 1);
    const ushort* gA = A + (size_t)sar * K + (wid & 1)*32 + lq*8;
    ushort* lA = As + wid*512;
    const ushort* gB[4];
    ushort* lB[4];
#pragma unroll
    for (int i = 0; i < 4; i++) {
        int g = wid*4 + i;
        gB[i] = Bt + (size_t)((g >> 1)*16 + lr) * K + (g & 1)*32 + lq*8;
        lB[i] = Bs + g*512;
    }

    f32x4 acc[2][4] = {};

    for (int k0 = 0; k0 < K; k0 += 64) {
        __syncthreads();               // prev-chunk reads done
        gload16(gA + k0, lA);
#pragma unroll
        for (int i = 0; i < 4; i++) gload16(gB[i] + k0, lB[i]);
        __syncthreads();               // stage complete
#pragma unroll
        for (int kg = 0; kg < 2; kg++) {
            bf16x8 af[2];
#pragma unroll
            for (int mi = 0; mi < 2; mi++)
                af[mi] = *(const bf16x8*)&As[((wm*2 + mi)*2 + kg)*512 + l*8];
#pragma unroll
            for (int ni = 0; ni < 4; ni++) {
                bf16x8 bv = *(const bf16x8*)&Bs[((wn*4 + ni)*2 + kg)*512 + l*8];
#pragma unroll
                for (int mi = 0; mi < 2; mi++)
                    acc[mi][ni] = __builtin_amdgcn_mfma_f32_16x16x32_bf16(
                        af[mi], bv, acc[mi][ni], 0, 0, 0);
            }
        }
    }

    __syncthreads();   // all MFMA reads of As done; red arrays alias As
    float* red1 = (float*)As;          // [4][64] = 1KB
    float* red2 = red1 + 256;          // [4][64] = 1KB  (2KB <= 8KB As)

    // epilogue: bias/res/addC -> LN stats (cross-wave over wn) -> dual write
    float biasv[4], gv[4], bvv[4];
#pragma unroll
    for (int ni = 0; ni < 4; ni++) {
        int col = wn*64 + ni*16 + lr;
        biasv[ni] = bias[col]; gv[ni] = gam[col]; bvv[ni] = bet[col];
    }
#pragma unroll
    for (int mi = 0; mi < 2; mi++)
#pragma unroll
        for (int j = 0; j < 4; j++) {
            int row = row0 + wm*32 + mi*16 + lq*4 + j;
            bool ok = row < Mrows;
#pragma unroll
            for (int ni = 0; ni < 4; ni++) {
                float v = acc[mi][ni][j] + biasv[ni];
                size_t ci = (size_t)row * 256 + wn*64 + ni*16 + lr;
                if (ok) {
                    if (res)  v += res[ci];
                    if (addC) v += Cout[ci];
                }
                acc[mi][ni][j] = v;
            }
        }
#pragma unroll
    for (int mi = 0; mi < 2; mi++)
#pragma unroll
        for (int j = 0; j < 4; j++) {
            float s1 = 0.f, s2 = 0.f;
#pragma unroll
            for (int ni = 0; ni < 4; ni++) {
                float v = acc[mi][ni][j];
                s1 += v; s2 += v*v;
            }
#pragma unroll
            for (int off = 1; off < 16; off <<= 1) {
                s1 += __shfl_xor(s1, off);
                s2 += __shfl_xor(s2, off);
            }
            if (lr == 0) {
                int r = wm*32 + mi*16 + lq*4 + j;
                red1[wn*64 + r] = s1;
                red2[wn*64 + r] = s2;
            }
        }
    __syncthreads();
#pragma unroll
    for (int mi = 0; mi < 2; mi++)
#pragma unroll
        for (int j = 0; j < 4; j++) {
            int r = wm*32 + mi*16 + lq*4 + j;
            int row = row0 + r;
            if (row >= Mrows) continue;
            float m1 = (red1[r]+red1[64+r]+red1[128+r]+red1[192+r]) * (1.f/256.f);
            float m2 = (red2[r]+red2[64+r]+red2[128+r]+red2[192+r]) * (1.f/256.f);
            float inv = rsqrtf(m2 - m1*m1 + 1e-5f);
#pragma unroll
            for (int ni = 0; ni < 4; ni++) {
                size_t ci = (size_t)row * 256 + wn*64 + ni*16 + lr;
                float v = acc[mi][ni][j];
                Cout[ci] = v;
                ABout[ci] = f2bf((v - m1)*inv*gv[ni] + bvv[ni]);
            }
        }
}

// ------------------------------------------------- sample embedding (split)
__global__ __launch_bounds__(256) void k_zero(float* __restrict__ p, int n) {
    int i = blockIdx.x*256 + threadIdx.x;
    if (i < n) p[i] = 0.f;
}

__global__ __launch_bounds__(256) void k_se1(const float* __restrict__ x,
    const float* __restrict__ w1, float* __restrict__ t1)
{
    const int blk = blockIdx.x, b = blockIdx.y, t = threadIdx.x;
    const int k0 = blk * 250;
    float acc = 0.f;
    for (int kk = 0; kk < 250; kk++) {
        float xv = x[b*Gg + k0 + kk];
        acc += xv * w1[(size_t)(k0 + kk)*256 + t];
    }
    atomicAdd(&t1[b*256 + t], acc);
}

__global__ __launch_bounds__(256) void k_se2(const float* __restrict__ t1,
    const float* __restrict__ b1, const float* __restrict__ w2,
    const float* __restrict__ b2, float* __restrict__ samp)
{
    const int b = blockIdx.x, t = threadIdx.x;
    __shared__ float s1[256];
    s1[t] = fmaxf(t1[b*256 + t] + b1[t], 0.f);
    __syncthreads();
    float acc = 0.f;
    for (int n = 0; n < 256; n++) acc += s1[n] * w2[(size_t)n*256 + t];
    samp[b*256 + t] = acc + b2[t];
}

// embed: one wave per row, 4 cols/lane.  grid (MB/4); batch decoded from row.
__global__ __launch_bounds__(256) void k_embed(const float* __restrict__ x,
    const float* __restrict__ gene_emb, const float* __restrict__ samp,
    ushort* __restrict__ outb, int b0)
{
    const int w = threadIdx.x >> 6, l = threadIdx.x & 63;
    const int mb = blockIdx.x * 4 + w;          // row within this pass
    const int bb = mb / Gg;                     // 0..NBP-1
    const int g  = mb - bb * Gg;
    const int b  = b0 + bb;
    const float xv = x[b*Gg + g];
    const int d0 = l * 4;
    float4 gev = *(const float4*)&gene_emb[(size_t)g*256 + d0];
    float4 sv  = *(const float4*)&samp[b*256 + d0];
    float gv[4] = {gev.x, gev.y, gev.z, gev.w};
    float sp[4] = {sv.x, sv.y, sv.z, sv.w};
    ushort4 o;
    ushort* op = (ushort*)&o;
#pragma unroll
    for (int i = 0; i < 4; i++) {
        int d = d0 + i, j = d & 127;
        float ang = xv * __expf(-(float)j * 0.035977892078032f);   // ln(100)/128
        float ree = (d < 128) ? __sinf(ang) : __cosf(ang);
        if (xv == -10.0f) ree = 0.f;
        op[i] = f2bf(gv[i] + ree + sp[i]);
    }
    *(ushort4*)&outb[(size_t)mb*256 + d0] = o;
}

// ------------------------------------------------- FAVOR+ (3 kernels, exact)
// ctx2: norm-bound local shift + E-sums + Sv + slot stores.  grid (NSLOT, 8*NBP)
__global__ __launch_bounds__(256) void k_ctx2(const ushort* __restrict__ qkv,
    const ushort* __restrict__ projb, const float* __restrict__ pnorm, int lidx,
    float* __restrict__ ctxp, float* __restrict__ ksp, float* __restrict__ svp,
    float* __restrict__ mlp)
{
    __shared__ ushort kpsT[128][72];
    __shared__ ushort vt[32][72];
    __shared__ float diag[192];
    __shared__ float sm[4];
    __shared__ float ksl[4][128];
    __shared__ float svl[8][32];
    const int bh = blockIdx.y, blk = blockIdx.x;
    const int h = bh & 7;
    const ushort* qkvb = qkv + (size_t)(bh >> 3) * Gg * QKVS;
    const int t = threadIdx.x, w = t >> 6, l = t & 63;
    const int lr = l & 15, lq = l >> 4;
    bf16x8 pb[8];
#pragma unroll
    for (int nt = 0; nt < 8; nt++)
        pb[nt] = *(const bf16x8*)(projb + (nt*16 + lr)*32 + lq*8);
    const int g0 = blk * NBLK;
    const int rows = min(NBLK, Gg - g0);
    f32x4 z = {};

    // ---- pass 0: load k-frags, row norms -> diag LDS + block max norm
    bf16x8 afs0 = {}, afs1 = {}, afs2 = {};
    float mx = 0.f;
    {
        int arow = min(g0 + w*16 + lr, Gg - 1);
        afs0 = *(const bf16x8*)(qkvb + (size_t)arow*QKVS + h*32 + lq*8);
        float s = 0.f;
#pragma unroll
        for (int j = 0; j < 8; j++) { float kv = bf2f((ushort)afs0[j]); s += kv*kv; }
        s += __shfl_xor(s, 16); s += __shfl_xor(s, 32);
        if (l < 16) diag[w*16 + l] = DN2H * s;
        mx = fmaxf(mx, s);
    }
    if (64 < rows) {
        int arow = min(g0 + 64 + w*16 + lr, Gg - 1);
        afs1 = *(const bf16x8*)(qkvb + (size_t)arow*QKVS + h*32 + lq*8);
        float s = 0.f;
#pragma unroll
        for (int j = 0; j < 8; j++) { float kv = bf2f((ushort)afs1[j]); s += kv*kv; }
        s += __shfl_xor(s, 16); s += __shfl_xor(s, 32);
        if (l < 16) diag[64 + w*16 + l] = DN2H * s;
        mx = fmaxf(mx, s);
    }
    if (128 < rows) {
        int arow = min(g0 + 128 + w*16 + lr, Gg - 1);
        afs2 = *(const bf16x8*)(qkvb + (size_t)arow*QKVS + h*32 + lq*8);
        float s = 0.f;
#pragma unroll
        for (int j = 0; j < 8; j++) { float kv = bf2f((ushort)afs2[j]); s += kv*kv; }
        s += __shfl_xor(s, 16); s += __shfl_xor(s, 32);
        if (l < 16) diag[128 + w*16 + l] = DN2H * s;
        mx = fmaxf(mx, s);
    }
#pragma unroll
    for (int off = 1; off < 64; off <<= 1) mx = fmaxf(mx, __shfl_xor(mx, off));
    if (l == 0) sm[w] = mx;
    __syncthreads();
    const float mloc = DN * sqrtf(fmaxf(fmaxf(sm[0], sm[1]), fmaxf(sm[2], sm[3])))
                     * pnorm[lidx];
    if (t == 0) mlp[bh*NSLOT + blk] = mloc;

    // ---- pass 2: E accumulate
    f32x4 cacc[2][2] = {};
    float ksacc[8] = {};
    float svacc = 0.f;
#pragma unroll
    for (int c = 0; c < 3; c++) {
        if (c*64 >= rows) break;
        bf16x8 af = (c == 0) ? afs0 : (c == 1) ? afs1 : afs2;
        const int nr = min(64, rows - c*64);
        const int rbase = g0 + c*64;
        f32x4 dd[8];
#pragma unroll
        for (int nt = 0; nt < 8; nt++)
            dd[nt] = __builtin_amdgcn_mfma_f32_16x16x32_bf16(af, pb[nt], z, 0, 0, 0);
        __syncthreads();   // prev-chunk kpsT/vt reads done
        float dg[4];
#pragma unroll
        for (int j = 0; j < 4; j++) dg[j] = diag[c*64 + w*16 + lq*4 + j];
#pragma unroll
        for (int nt = 0; nt < 8; nt++) {
            ushort4 kp4;
            ushort* kpp = (ushort*)&kp4;
#pragma unroll
            for (int j = 0; j < 4; j++) {
                int rj = w*16 + lq*4 + j;
                float e = 0.f;
                if (rj < nr) e = __expf(DN*dd[nt][j] - dg[j] - mloc);
                ksacc[nt] += e;
                kpp[j] = f2bf(e);
            }
            *(ushort4*)&kpsT[nt*16 + lr][w*16 + lq*4] = kp4;
        }
        for (int i = t; i < 512; i += 256) {
            int r = i >> 3, c4 = (i & 7) * 4;
            ushort4 vv = make_ushort4(0, 0, 0, 0);
            if (r < nr)
                vv = *(const ushort4*)(qkvb + (size_t)(rbase + r)*QKVS + 256 + h*32 + c4);
            vt[c4+0][r] = vv.x; vt[c4+1][r] = vv.y;
            vt[c4+2][r] = vv.z; vt[c4+3][r] = vv.w;
        }
        __syncthreads();   // kpsT + vt ready
        {
            int dh = t & 31, gs = (t >> 5) * 8;
            float p = 0.f;
#pragma unroll
            for (int i = 0; i < 8; i++) p += bf2f(vt[dh][gs + i]);
            svacc += p;
        }
#pragma unroll
        for (int ks = 0; ks < 2; ks++) {
            bf16x8 a0 = *(const bf16x8*)&vt[lr][ks*32 + lq*8];
            bf16x8 a1 = *(const bf16x8*)&vt[16 + lr][ks*32 + lq*8];
#pragma unroll
            for (int ntp = 0; ntp < 2; ntp++) {
                bf16x8 bfr = *(const bf16x8*)&kpsT[(w*2 + ntp)*16 + lr][ks*32 + lq*8];
                cacc[0][ntp] = __builtin_amdgcn_mfma_f32_16x16x32_bf16(a0, bfr, cacc[0][ntp], 0, 0, 0);
                cacc[1][ntp] = __builtin_amdgcn_mfma_f32_16x16x32_bf16(a1, bfr, cacc[1][ntp], 0, 0, 0);
            }
        }
    }
    // ---- slot stores (all plain)
    float* cslot = ctxp + (size_t)(bh*NSLOT + blk)*4096;
#pragma unroll
    for (int dt = 0; dt < 2; dt++)
#pragma unroll
        for (int ntp = 0; ntp < 2; ntp++)
#pragma unroll
            for (int j = 0; j < 4; j++)
                cslot[(dt*16 + lq*4 + j)*128 + (w*2 + ntp)*16 + lr] = cacc[dt][ntp][j];
#pragma unroll
    for (int nt = 0; nt < 8; nt++) {
        float v = ksacc[nt];
        v += __shfl_xor(v, 16); v += __shfl_xor(v, 32);
        if (l < 16) ksl[w][nt*16 + l] = v;
    }
    svl[t >> 5][t & 31] = svacc;
    __syncthreads();
    if (t < 128)
        ksp[(size_t)(bh*NSLOT + blk)*128 + t] = ksl[0][t] + ksl[1][t] + ksl[2][t] + ksl[3][t];
    if (t < 32) {
        float sv = 0.f;
#pragma unroll
        for (int i = 0; i < 8; i++) sv += svl[i][t];
        svp[(size_t)(bh*NSLOT + blk)*32 + t] = sv;
    }
}

// cred2: exact global-shift fixup -> ctx bf16, ksum fp32.  grid (16, 8*NBP)
__global__ __launch_bounds__(256) void k_cred2(const float* __restrict__ ctxp,
    const float* __restrict__ ksp, const float* __restrict__ svp,
    const float* __restrict__ mlp, ushort* __restrict__ ctxbg,
    float* __restrict__ ksum)
{
    __shared__ float mls[NSLOT];
    __shared__ float sc[NSLOT];
    __shared__ float svt[32];
    const int bh = blockIdx.y, blk = blockIdx.x, t = threadIdx.x;
    if (t < NSLOT) mls[t] = mlp[bh*NSLOT + t];
    __syncthreads();
    float km = -1e30f;
    for (int s = 0; s < NSLOT; s++) km = fmaxf(km, mls[s]);
    if (t < NSLOT) sc[t] = __expf(mls[t] - km);
    if (t < 32) {
        float sv = 0.f;
        for (int s = 0; s < NSLOT; s++) sv += svp[(size_t)(bh*NSLOT + s)*32 + t];
        svt[t] = sv;
    }
    __syncthreads();
    const int i = blk*256 + t;
    float acc = 0.f;
    for (int s = 0; s < NSLOT; s++)
        acc += sc[s] * ctxp[(size_t)(bh*NSLOT + s)*4096 + i];
    ctxbg[bh*4096 + i] = f2bf(RATIO * (acc + EPSK * svt[i >> 7]));
    if (blk == 0 && t < 128) {
        float ka = 0.f;
        for (int s = 0; s < NSLOT; s++)
            ka += sc[s] * ksp[(size_t)(bh*NSLOT + s)*128 + t];
        ksum[bh*128 + t] = RATIO * (ka + EPSK * (float)Gg);
    }
}

// attn: o = dinv * (qp @ ctx).  grid (NSLOT, 8*NBP)
__global__ __launch_bounds__(256) void k_attn(const ushort* __restrict__ qkv,
    const ushort* __restrict__ projb, const ushort* __restrict__ ctxbg,
    const float* __restrict__ ksum, ushort* __restrict__ obuf)
{
    __shared__ ushort qps[64][136];
    __shared__ float ksl[128];
    __shared__ float dgq[64];
    const int bh = blockIdx.y, blk = blockIdx.x;
    const int h = bh & 7;
    const ushort* qkvb = qkv + (size_t)(bh >> 3) * Gg * QKVS;
    ushort* obufb = obuf + (size_t)(bh >> 3) * Gg * 256;
    const int t = threadIdx.x, w = t >> 6, l = t & 63;
    const int lr = l & 15, lq = l >> 4;
    bf16x8 pb[8];
#pragma unroll
    for (int nt = 0; nt < 8; nt++)
        pb[nt] = *(const bf16x8*)(projb + (nt*16 + lr)*32 + lq*8);
    if (t < 128) ksl[t] = ksum[bh*128 + t];
    bf16x8 cb[2][4];
#pragma unroll
    for (int dt = 0; dt < 2; dt++)
#pragma unroll
        for (int ks = 0; ks < 4; ks++)
            cb[dt][ks] = *(const bf16x8*)(ctxbg + bh*4096 + (dt*16 + lr)*128 + ks*32 + lq*8);
    __syncthreads();
    const int g0 = blk * NBLK;
    const int rows = min(NBLK, Gg - g0);
    f32x4 z = {};
    for (int gc = 0; gc < rows; gc += 64) {
        const int nr = min(64, rows - gc);
        const int rbase = g0 + gc;
        int arow = min(rbase + w*16 + lr, Gg - 1);
        bf16x8 af = *(const bf16x8*)(qkvb + (size_t)arow*QKVS + 512 + h*32 + lq*8);
        float s = 0.f;
#pragma unroll
        for (int j = 0; j < 8; j++) { float qv = bf2f((ushort)af[j]); s += qv*qv; }
        s += __shfl_xor(s, 16); s += __shfl_xor(s, 32);
        if (l < 16) dgq[w*16 + l] = DN2H * s;
        f32x4 dd[8];
#pragma unroll
        for (int nt = 0; nt < 8; nt++)
            dd[nt] = __builtin_amdgcn_mfma_f32_16x16x32_bf16(af, pb[nt], z, 0, 0, 0);
        __syncthreads();   // dgq ready; prev-chunk qps reads done
        float dg[4], mq[4], den[4], dinv[4];
#pragma unroll
        for (int j = 0; j < 4; j++) {
            dg[j] = dgq[w*16 + lq*4 + j];
            float m = -1e30f;
#pragma unroll
            for (int nt = 0; nt < 8; nt++) m = fmaxf(m, dd[nt][j]);
            mq[j] = m;
        }
#pragma unroll
        for (int off = 1; off < 16; off <<= 1)
#pragma unroll
            for (int j = 0; j < 4; j++) mq[j] = fmaxf(mq[j], __shfl_xor(mq[j], off));
#pragma unroll
        for (int j = 0; j < 4; j++) { mq[j] = DN*mq[j]; den[j] = 0.f; }
#pragma unroll
        for (int nt = 0; nt < 8; nt++) {
            float kv = ksl[nt*16 + lr];
#pragma unroll
            for (int j = 0; j < 4; j++) {
                float p = RATIO * (__expf(DN*dd[nt][j] - dg[j] - mq[j]) + EPSK);
                dd[nt][j] = p;
                den[j] += p * kv;
            }
        }
#pragma unroll
        for (int off = 1; off < 16; off <<= 1)
#pragma unroll
            for (int j = 0; j < 4; j++) den[j] += __shfl_xor(den[j], off);
#pragma unroll
        for (int j = 0; j < 4; j++) dinv[j] = 1.f / den[j];
#pragma unroll
        for (int nt = 0; nt < 8; nt++)
#pragma unroll
            for (int j = 0; j < 4; j++)
                qps[w*16 + lq*4 + j][nt*16 + lr] = f2bf(dd[nt][j]);
        __syncthreads();
        f32x4 oacc[2] = {};
#pragma unroll
        for (int ks = 0; ks < 4; ks++) {
            bf16x8 aq = *(const bf16x8*)&qps[w*16 + lr][ks*32 + lq*8];
            oacc[0] = __builtin_amdgcn_mfma_f32_16x16x32_bf16(aq, cb[0][ks], oacc[0], 0, 0, 0);
            oacc[1] = __builtin_amdgcn_mfma_f32_16x16x32_bf16(aq, cb[1][ks], oacc[1], 0, 0, 0);
        }
#pragma unroll
        for (int dt = 0; dt < 2; dt++)
#pragma unroll
            for (int j = 0; j < 4; j++) {
                int rj = w*16 + lq*4 + j;
                if (rj < nr)
                    obufb[(size_t)(rbase + rj)*256 + h*32 + dt*16 + lr]
                        = f2bf(oacc[dt][j] * dinv[j]);
            }
    }
}

// ------------------------------------------------- head dot: out = relu(u.w2 + b2)
// 512 thr, 8 rows/block (1 wave per row), 16 bf16/lane.  grid ceil(M/8).
__global__ __launch_bounds__(512) void k_headd(const ushort* __restrict__ u,
    const float* __restrict__ w2, const float* __restrict__ b2,
    float* __restrict__ outp, int Mrows)
{
    const int w = threadIdx.x >> 6, l = threadIdx.x & 63;
    const int row = blockIdx.x * 8 + w;
    if (row >= Mrows) return;
    const ushort* up = u + (size_t)row * 1024 + l * 16;
    const float*  wp = w2 + l * 16;
    float acc = 0.f;
#pragma unroll
    for (int i = 0; i < 2; i++) {
        uint4 uv = *(const uint4*)(up + i*8);
        const ushort* us = (const ushort*)&uv;
        float4 w0 = *(const float4*)(wp + i*8);
        float4 w1 = *(const float4*)(wp + i*8 + 4);
        acc += bf2f(us[0])*w0.x + bf2f(us[1])*w0.y
             + bf2f(us[2])*w0.z + bf2f(us[3])*w0.w
             + bf2f(us[4])*w1.x + bf2f(us[5])*w1.y
             + bf2f(us[6])*w1.z + bf2f(us[7])*w1.w;
    }
#pragma unroll
    for (int off = 1; off < 64; off <<= 1) acc += __shfl_xor(acc, off);
    if (l == 0) outp[row] = fmaxf(acc + b2[0], 0.f);
}

// ---------------------------------------------------------------- launch
extern "C" void kernel_launch(void* const* d_in, const int* in_sizes, int n_in,
                              void* d_out, int out_size, void* d_ws, size_t ws_size,
                              hipStream_t stream)
{
    const float* x        = (const float*)d_in[0];
    const float* gene_emb = (const float*)d_in[1];
    const float* se_w1    = (const float*)d_in[2];
    const float* se_b1    = (const float*)d_in[3];
    const float* se_w2    = (const float*)d_in[4];
    const float* se_b2    = (const float*)d_in[5];
    const float* proj_b1  = (const float*)d_in[7];
    const float* proj_b2  = (const float*)d_in[9];
    const float* ln1_g    = (const float*)d_in[10];
    const float* ln1_b    = (const float*)d_in[11];
    const float* bo       = (const float*)d_in[16];
    const float* ln2_g    = (const float*)d_in[17];
    const float* ln2_b    = (const float*)d_in[18];
    const float* ff_b1    = (const float*)d_in[20];
    const float* ff_b2    = (const float*)d_in[22];
    const float* featp    = (const float*)d_in[23];
    const float* norm_g   = (const float*)d_in[24];
    const float* norm_b   = (const float*)d_in[25];
    const float* head_b1  = (const float*)d_in[27];
    const float* head_w2  = (const float*)d_in[28];
    const float* head_b2  = (const float*)d_in[29];
    const float* wq  = (const float*)d_in[12];
    const float* wk  = (const float*)d_in[13];
    const float* wv  = (const float*)d_in[14];
    const float* wo  = (const float*)d_in[15];
    const float* ff_w1 = (const float*)d_in[19];
    const float* ff_w2 = (const float*)d_in[21];
    const float* proj_w1 = (const float*)d_in[6];
    const float* proj_w2 = (const float*)d_in[8];
    const float* head_w1 = (const float*)d_in[26];
    float* out = (float*)d_out;

    // ---- adaptive multi-batch: NBP=4 needs ~377 MB; NBP=2 ~210 MB; else NBP=1
    const int NBP  = (ws_size >= (size_t)380000000) ? 4
                   : (ws_size >= (size_t)185000000) ? 2 : 1;
    const int MB   = NBP * Gg;
    const int CHKF = (NBP == 4) ? 80000
                   : (NBP == 2 && ws_size >= (size_t)210000000) ? 40000
                   : (NBP == 2 || ws_size >= (size_t)102000000) ? 20000 : 10000;
    const int NCHF = MB / CHKF;
    const int NPASS = Bb / NBP;
    // pad between B1 and Ab must hold samp+t1+ksum+ctxbg+pnormb
    const size_t PADF = (NBP == 4) ? 81920 : 40000;

    float* w = (float*)d_ws;
    const size_t SBm = (size_t)MB * Dd;
    float* f_h  = w;                             // [MB,256] fp32 residual
    float* B1   = w + SBm;                       // [MB,256] fp32 y; attn slots alias
    float* samp = w + 2*SBm;                     // 2048
    float* t1   = samp + 2048;                   // 2048
    float* ksum = t1 + 2048;                     // NBP*1024
    ushort* ctxbg = (ushort*)(ksum + NBP*1024);  // NBP*8*4096 ushorts
    float* pnormb = (float*)(ctxbg + NBP*32768); // 4
    ushort* Ab  = (ushort*)(w + 2*SBm + PADF);   // [MB,256] bf16
    ushort* U   = Ab + SBm;                      // QKV [MB,768] | B4 [CHKF,1024]
    const size_t usz = (size_t)MB * QKVS > (size_t)CHKF * FFf
                     ? (size_t)MB * QKVS : (size_t)CHKF * FFf;
    ushort* Wt  = U + usz;                       // 3,932,160 bf16
    ushort* projb = Wt + 3932160;                // 16384 bf16
    ushort* QKVb = U;
    ushort* B4   = U;
    float* ctxp = B1;                            // NBP*NSLOT*8 x 4096
    float* ksp  = B1 + (size_t)NBP*NSLOT*8*4096;
    float* svp  = ksp + (size_t)NBP*NSLOT*8*128;
    float* mlp  = svp + (size_t)NBP*NSLOT*8*32;

    const size_t LW = 786432;
    ushort* pj1T = Wt + 4*LW;
    ushort* pj2T = pj1T + 262144;
    ushort* hd1T = pj2T + 262144;

    auto gemmb = [&](const ushort* A, const ushort* Bt, const float* bias,
                     ushort* C, int Mr, int N, int K, int act) {
        gemm_bf<<<dim3(N/128, (Mr + 127)/128), 512, 0, stream>>>(A, Bt, bias, C, Mr, N, K, act);
    };
    auto gemml = [&](const ushort* A, const ushort* Bt, const float* bias,
                     const float* res, float* Cout, ushort* ABout,
                     const float* g, const float* be, int Mr, int K, int addC) {
        gemm_ln<<<dim3((Mr + 63)/64), 512, 0, stream>>>(A, Bt, bias, res, Cout, ABout,
                                                        g, be, Mr, K, addC);
    };

    // ---- weight casts + proj norms + sample embedding (parallel split)
    k_wt4<<<dim3(8, 8, 16), 256, 0, stream>>>(wk, wv, wq, wo, Wt);
    k_wtA<<<dim3(32, 8, 6), 256, 0, stream>>>(ff_w1, proj_w1, head_w1, Wt);
    k_wtB<<<dim3(8, 32, 5), 256, 0, stream>>>(ff_w2, proj_w2, Wt);
    k_pcast<<<64, 256, 0, stream>>>(featp, projb, Ll*Mm*DHh);
    k_pn<<<4, 128, 0, stream>>>(featp, pnormb);
    k_zero<<<8, 256, 0, stream>>>(t1, 2048);
    k_se1<<<dim3(80, 8), 256, 0, stream>>>(x, se_w1, t1);
    k_se2<<<8, 256, 0, stream>>>(t1, se_b1, se_w2, se_b2, samp);

    // ---- per pass (NBP batches) full network
    for (int p = 0; p < NPASS; p++) {
        k_embed<<<MB/4, 256, 0, stream>>>(x, gene_emb, samp, Ab, p*NBP);
        for (int c = 0; c < NCHF; c++) {
            size_t off = (size_t)c * CHKF * Dd;
            gemmb(Ab + off, pj1T, proj_b1, B4, CHKF, FFf, Dd, 1);
            gemml(B4, pj2T, proj_b2, nullptr, f_h + off, Ab + off,
                  ln1_g, ln1_b, CHKF, FFf, 0);
        }
        for (int l = 0; l < Ll; l++) {
            ushort* lw = Wt + (size_t)l * LW;
            const ushort* qkvT = lw;
            const ushort* oT   = lw + 196608;
            const ushort* f1T  = lw + 262144;
            const ushort* f2T  = lw + 524288;
            const ushort* pjb  = projb + (size_t)l*Mm*DHh;
            const float* gn = (l < Ll-1) ? ln1_g + (l+1)*Dd : norm_g;
            const float* bn = (l < Ll-1) ? ln1_b + (l+1)*Dd : norm_b;

            gemmb(Ab, qkvT, nullptr, QKVb, MB, QKVS, Dd, 0);
            k_ctx2<<<dim3(NSLOT, 8*NBP), 256, 0, stream>>>(QKVb, pjb, pnormb, l,
                                                           ctxp, ksp, svp, mlp);
            k_cred2<<<dim3(16, 8*NBP), 256, 0, stream>>>(ctxp, ksp, svp, mlp,
                                                         ctxbg, ksum);
            k_attn<<<dim3(NSLOT, 8*NBP), 256, 0, stream>>>(QKVb, pjb, ctxbg, ksum, Ab);
            gemml(Ab, oT, bo + l*Dd, f_h, B1, Ab,
                  ln2_g + l*Dd, ln2_b + l*Dd, MB, Dd, 0);
            for (int c = 0; c < NCHF; c++) {
                size_t off = (size_t)c * CHKF * Dd;
                gemmb(Ab + off, f1T, ff_b1 + l*FFf, B4, CHKF, FFf, Dd, 2);
                gemml(B4, f2T, ff_b2 + l*Dd, B1 + off, f_h + off, Ab + off,
                      gn, bn, CHKF, FFf, 1);
            }
        }
        // head: u = relu(Ab@hd1 + b1) via proven gemm_bf, then lean dot kernel.
        gemmb(Ab, hd1T, head_b1, B4, MB, FFf, Dd, 1);
        k_headd<<<(MB + 7)/8, 512, 0, stream>>>(B4, head_w2, head_b2,
                                                out + (size_t)p*MB, MB);
    }
}